// Round 6
// baseline (423.089 us; speedup 1.0000x reference)
//
#include <hip/hip_runtime.h>
#include <math.h>

#define D_H 128

typedef __attribute__((ext_vector_type(8))) __bf16 bf16x8;
typedef __attribute__((ext_vector_type(4))) float f32x4;

__device__ __forceinline__ void split_bf16(float v, unsigned short& hi, unsigned short& lo) {
  unsigned int u = __float_as_uint(v);
  hi = (unsigned short)(u >> 16);
  float l = v - __uint_as_float(u & 0xffff0000u);
  lo = (unsigned short)(__float_as_uint(l) >> 16);
}

// pack 8 floats -> hi bf16x8 + lo bf16x8 (truncation split)
__device__ __forceinline__ void pack_pair8(const float* xv, bf16x8& ah, bf16x8& al) {
  union { bf16x8 v; unsigned int u[4]; } H, L;
#pragma unroll
  for (int e = 0; e < 4; ++e) {
    unsigned int u0 = __float_as_uint(xv[2 * e]);
    unsigned int u1 = __float_as_uint(xv[2 * e + 1]);
    float l0 = xv[2 * e] - __uint_as_float(u0 & 0xffff0000u);
    float l1 = xv[2 * e + 1] - __uint_as_float(u1 & 0xffff0000u);
    H.u[e] = (u0 >> 16) | (u1 & 0xffff0000u);
    L.u[e] = (__float_as_uint(l0) >> 16) | (__float_as_uint(l1) & 0xffff0000u);
  }
  ah = H.v;
  al = L.v;
}

// ---------------- graph build ----------------

__global__ void k_deg(const int* __restrict__ dstv, int* __restrict__ deg, int E) {
  for (int i = blockIdx.x * blockDim.x + threadIdx.x; i < E; i += gridDim.x * blockDim.x)
    atomicAdd(&deg[dstv[i]], 1);
}

__global__ __launch_bounds__(256) void k_partial(const int* __restrict__ deg,
                                                 int* __restrict__ partials, int N) {
  __shared__ int s[256];
  int t = threadIdx.x;
  int i = blockIdx.x * 256 + t;
  s[t] = (i < N) ? deg[i] : 0;
  __syncthreads();
  for (int off = 128; off > 0; off >>= 1) {
    if (t < off) s[t] += s[t + off];
    __syncthreads();
  }
  if (t == 0) partials[blockIdx.x] = s[0];
}

__global__ __launch_bounds__(256) void k_scanpart(int* __restrict__ partials, int NB,
                                                  int* __restrict__ row_ptr, int N) {
  __shared__ int s[256];
  int t = threadIdx.x;
  int v = (t < NB) ? partials[t] : 0;
  s[t] = v;
  __syncthreads();
  for (int off = 1; off < 256; off <<= 1) {
    int u = (t >= off) ? s[t - off] : 0;
    __syncthreads();
    s[t] += u;
    __syncthreads();
  }
  if (t < NB) partials[t] = s[t] - v;
  if (t == 255) row_ptr[N] = s[255];
}

__global__ __launch_bounds__(256) void k_rowptr(const int* __restrict__ deg,
                                                const int* __restrict__ partials,
                                                int* __restrict__ row_ptr,
                                                int* __restrict__ cnt, int N) {
  __shared__ int s[256];
  int t = threadIdx.x;
  int i = blockIdx.x * 256 + t;
  int v = (i < N) ? deg[i] : 0;
  s[t] = v;
  __syncthreads();
  for (int off = 1; off < 256; off <<= 1) {
    int u = (t >= off) ? s[t - off] : 0;
    __syncthreads();
    s[t] += u;
    __syncthreads();
  }
  if (i < N) {
    int ex = partials[blockIdx.x] + s[t] - v;
    row_ptr[i] = ex;
    cnt[i] = ex;
  }
}

__global__ void k_scatter(const int* __restrict__ srcv, const int* __restrict__ dstv,
                          int* __restrict__ cnt, int* __restrict__ col, int E) {
  for (int i = blockIdx.x * blockDim.x + threadIdx.x; i < E; i += gridDim.x * blockDim.x) {
    int d = dstv[i];
    int pos = atomicAdd(&cnt[d], 1);
    col[pos] = srcv[i];
  }
}

// ---------------- weight split (once) ----------------
// emb: [128][640 shorts] = [320 hi | 320 lo] (K padded 300->320, zeros)
// conv: [128][256 shorts] = [128 hi | 128 lo]

__global__ __launch_bounds__(256) void k_wsplit(
    const float* __restrict__ Wemb, const float* __restrict__ Wl0,
    const float* __restrict__ Wr0, const float* __restrict__ Wl1,
    const float* __restrict__ Wr1, unsigned short* __restrict__ WembP,
    unsigned short* __restrict__ P0l, unsigned short* __restrict__ P0r,
    unsigned short* __restrict__ P1l, unsigned short* __restrict__ P1r) {
  int tid = blockIdx.x * 256 + threadIdx.x;
  const int EMB = 128 * 320;
  if (tid < EMB) {
    int o = tid / 320, k = tid - o * 320;
    float v = (k < 300) ? Wemb[o * 300 + k] : 0.f;
    unsigned short h, l;
    split_bf16(v, h, l);
    WembP[o * 640 + k] = h;
    WembP[o * 640 + 320 + k] = l;
  } else if (tid < EMB + 4 * 16384) {
    int r = tid - EMB;
    int m = r >> 14;
    int i = r & 16383;
    int o = i >> 7, k = i & 127;
    const float* W = (m == 0) ? Wl0 : (m == 1) ? Wr0 : (m == 2) ? Wl1 : Wr1;
    unsigned short* P = (m == 0) ? P0l : (m == 1) ? P0r : (m == 2) ? P1l : P1r;
    unsigned short h, l;
    split_bf16(W[o * 128 + k], h, l);
    P[o * 256 + k] = h;
    P[o * 256 + 128 + k] = l;
  }
}

// ---------------- emb GEMM: P = pair( x @ Wemb^T + b ) ----------------
// Block = 32 rows, 4 waves = 2wr x 2wc; wave = 16 rows x 64 cols (1x4 frags).
// Depth-1 register prefetch on x; W loads batched per step. No main-loop LDS.

__global__ __launch_bounds__(256, 4) void k_emb(const float* __restrict__ x,
                                                const unsigned short* __restrict__ Wp,
                                                const float* __restrict__ bias,
                                                unsigned short* __restrict__ P, int N) {
  int t = threadIdx.x, lane = t & 63, wave = t >> 6;
  int wr = wave >> 1, wc = wave & 1;
  int row0 = blockIdx.x * 32;
  int fr = lane & 15, q4 = lane >> 4;
  int fk = q4 * 8, fob = q4 * 16;
  int row = row0 + wr * 16 + fr;
  if (row >= N) row = N - 1;
  const float* xrp = x + (size_t)row * 300;
  f32x4 acc[4] = {};
  float xb[2][8];

  auto loadx = [&](float* d, int c0) {
    if (c0 + 7 < 300) {
      float4 a = *(const float4*)(xrp + c0);
      float4 b = *(const float4*)(xrp + c0 + 4);
      d[0] = a.x; d[1] = a.y; d[2] = a.z; d[3] = a.w;
      d[4] = b.x; d[5] = b.y; d[6] = b.z; d[7] = b.w;
    } else {
#pragma unroll
      for (int e = 0; e < 8; ++e) d[e] = (c0 + e < 300) ? xrp[c0 + e] : 0.f;
    }
  };

  loadx(xb[0], fk);
#pragma unroll
  for (int ks = 0; ks < 10; ++ks) {
    if (ks < 9) loadx(xb[(ks + 1) & 1], (ks + 1) * 32 + fk);
    bf16x8 bh[4], bl[4];
#pragma unroll
    for (int j = 0; j < 4; ++j) {
      const char* wb = (const char*)Wp + (size_t)(wc * 64 + j * 16 + fr) * 1280 + ks * 64 + fob;
      bh[j] = *(const bf16x8*)wb;
      bl[j] = *(const bf16x8*)(wb + 640);
    }
    bf16x8 ah, al;
    pack_pair8(xb[ks & 1], ah, al);
#pragma unroll
    for (int j = 0; j < 4; ++j) {
      acc[j] = __builtin_amdgcn_mfma_f32_16x16x32_bf16(ah, bh[j], acc[j], 0, 0, 0);
      acc[j] = __builtin_amdgcn_mfma_f32_16x16x32_bf16(ah, bl[j], acc[j], 0, 0, 0);
      acc[j] = __builtin_amdgcn_mfma_f32_16x16x32_bf16(al, bh[j], acc[j], 0, 0, 0);
    }
  }

  // epilogue: acc -> LDS f32 [32][133] -> packed pair stores (2x16B per thread)
  __shared__ float T[32 * 133];
#pragma unroll
  for (int j = 0; j < 4; ++j) {
    float b = bias[wc * 64 + j * 16 + fr];
#pragma unroll
    for (int rg = 0; rg < 4; ++rg)
      T[(wr * 16 + q4 * 4 + rg) * 133 + wc * 64 + j * 16 + fr] = acc[j][rg] + b;
  }
  __syncthreads();
  int r = t & 31, qq = t >> 5;
  float vals[16];
#pragma unroll
  for (int c = 0; c < 16; ++c) vals[c] = T[r * 133 + qq * 16 + c];
  unsigned int hu[8], lu[8];
#pragma unroll
  for (int e = 0; e < 8; ++e) {
    unsigned int u0 = __float_as_uint(vals[2 * e]);
    unsigned int u1 = __float_as_uint(vals[2 * e + 1]);
    float l0 = vals[2 * e] - __uint_as_float(u0 & 0xffff0000u);
    float l1 = vals[2 * e + 1] - __uint_as_float(u1 & 0xffff0000u);
    hu[e] = (u0 >> 16) | (u1 & 0xffff0000u);
    lu[e] = (__float_as_uint(l0) >> 16) | (__float_as_uint(l1) & 0xffff0000u);
  }
  char* rowp = (char*)P + (size_t)(row0 + r) * 512;
  uint4* dh = (uint4*)(rowp + qq * 32);
  uint4* dl = (uint4*)(rowp + 256 + qq * 32);
  dh[0] = make_uint4(hu[0], hu[1], hu[2], hu[3]);
  dh[1] = make_uint4(hu[4], hu[5], hu[6], hu[7]);
  dl[0] = make_uint4(lu[0], lu[1], lu[2], lu[3]);
  dl[1] = make_uint4(lu[4], lu[5], lu[6], lu[7]);
}

// ---------------- conv GEMM: U = A@Wl^T, V = A@Wr^T (fp32 out) ----------------
// Block = 32 rows, 4 waves = (om, wc); wave = 32 rows x 64 cols of U or V.
// Depth-1 register prefetch on A. K=128 (4 steps). No LDS.

__global__ __launch_bounds__(256, 4) void k_conv(const unsigned short* __restrict__ Ap,
                                                 const unsigned short* __restrict__ Wl,
                                                 const unsigned short* __restrict__ Wr,
                                                 float* __restrict__ U,
                                                 float* __restrict__ V) {
  int t = threadIdx.x, lane = t & 63, wave = t >> 6;
  int om = wave >> 1, wc = wave & 1;
  const unsigned short* W = om ? Wr : Wl;
  float* OUT = om ? V : U;
  int row0 = blockIdx.x * 32;
  int fr = lane & 15, q4 = lane >> 4;
  int fob = q4 * 16;
  f32x4 acc[2][4] = {};

  const char* ap0 = (const char*)Ap + (size_t)(row0 + fr) * 512 + fob;
  const char* ap1 = (const char*)Ap + (size_t)(row0 + 16 + fr) * 512 + fob;

  bf16x8 ah[2][2], al[2][2];
  ah[0][0] = *(const bf16x8*)ap0;
  al[0][0] = *(const bf16x8*)(ap0 + 256);
  ah[0][1] = *(const bf16x8*)ap1;
  al[0][1] = *(const bf16x8*)(ap1 + 256);

#pragma unroll
  for (int ks = 0; ks < 4; ++ks) {
    if (ks < 3) {
      int nb = (ks + 1) * 64;
      ah[(ks + 1) & 1][0] = *(const bf16x8*)(ap0 + nb);
      al[(ks + 1) & 1][0] = *(const bf16x8*)(ap0 + nb + 256);
      ah[(ks + 1) & 1][1] = *(const bf16x8*)(ap1 + nb);
      al[(ks + 1) & 1][1] = *(const bf16x8*)(ap1 + nb + 256);
    }
    bf16x8 bh[4], bl[4];
#pragma unroll
    for (int j = 0; j < 4; ++j) {
      const char* wb = (const char*)W + (size_t)(wc * 64 + j * 16 + fr) * 512 + ks * 64 + fob;
      bh[j] = *(const bf16x8*)wb;
      bl[j] = *(const bf16x8*)(wb + 256);
    }
#pragma unroll
    for (int j = 0; j < 4; ++j)
#pragma unroll
      for (int i = 0; i < 2; ++i) {
        acc[i][j] = __builtin_amdgcn_mfma_f32_16x16x32_bf16(ah[ks & 1][i], bh[j], acc[i][j], 0, 0, 0);
        acc[i][j] = __builtin_amdgcn_mfma_f32_16x16x32_bf16(ah[ks & 1][i], bl[j], acc[i][j], 0, 0, 0);
        acc[i][j] = __builtin_amdgcn_mfma_f32_16x16x32_bf16(al[ks & 1][i], bh[j], acc[i][j], 0, 0, 0);
      }
  }

#pragma unroll
  for (int i = 0; i < 2; ++i)
#pragma unroll
    for (int j = 0; j < 4; ++j)
#pragma unroll
      for (int rg = 0; rg < 4; ++rg)
        OUT[(size_t)(row0 + i * 16 + q4 * 4 + rg) * D_H + wc * 64 + j * 16 + fr] = acc[i][j][rg];
}

// ---------------- fused aggregate + epilogue ----------------
// h' = relu( mean-gather(U) + V + bias ); OUTP=1 -> pair out, OUTP=0 -> fp32
// in-place into V. One wave per node, float2 per lane.

template <int OUTP>
__global__ __launch_bounds__(256) void k_aggfin(const float* __restrict__ U,
                                                float* __restrict__ V,
                                                const float* __restrict__ bias,
                                                const int* __restrict__ row_ptr,
                                                const int* __restrict__ col,
                                                unsigned short* __restrict__ Hp, int N) {
  int wid = blockIdx.x * 4 + (threadIdx.x >> 6);
  if (wid >= N) return;
  int lane = threadIdx.x & 63;
  const float2* uv = (const float2*)U;
  int e0 = row_ptr[wid], e1 = row_ptr[wid + 1];
  float ax = 0.f, ay = 0.f;
  int e = e0;
  for (; e + 4 <= e1; e += 4) {
    int s0 = col[e], s1 = col[e + 1], s2 = col[e + 2], s3 = col[e + 3];
    float2 v0 = uv[(size_t)s0 * 64 + lane];
    float2 v1 = uv[(size_t)s1 * 64 + lane];
    float2 v2 = uv[(size_t)s2 * 64 + lane];
    float2 v3 = uv[(size_t)s3 * 64 + lane];
    ax += v0.x + v1.x + v2.x + v3.x;
    ay += v0.y + v1.y + v2.y + v3.y;
  }
  for (; e < e1; ++e) {
    float2 v = uv[(size_t)col[e] * 64 + lane];
    ax += v.x;
    ay += v.y;
  }
  float inv = 1.f / fmaxf((float)(e1 - e0), 1.f);
  float2 vv = ((const float2*)V)[(size_t)wid * 64 + lane];
  float2 bb = ((const float2*)bias)[lane];
  float ox = fmaxf(ax * inv + vv.x + bb.x, 0.f);
  float oy = fmaxf(ay * inv + vv.y + bb.y, 0.f);
  if (OUTP) {
    unsigned short hx, lx, hy, ly;
    split_bf16(ox, hx, lx);
    split_bf16(oy, hy, ly);
    ((unsigned int*)((char*)Hp + (size_t)wid * 512))[lane] =
        (unsigned int)hx | ((unsigned int)hy << 16);
    ((unsigned int*)((char*)Hp + (size_t)wid * 512 + 256))[lane] =
        (unsigned int)lx | ((unsigned int)ly << 16);
  } else {
    ((float2*)V)[(size_t)wid * 64 + lane] = make_float2(ox, oy);
  }
}

// ---------------- attention readout ----------------

__global__ __launch_bounds__(256) void k_score(const float* __restrict__ h,
                                               const float* __restrict__ watt,
                                               const float* __restrict__ batt,
                                               float* __restrict__ scores,
                                               float* __restrict__ partmax, int N) {
  __shared__ float smax[16];
  int t = threadIdx.x;
  int grp = t >> 4, l = t & 15;
  int node = blockIdx.x * 16 + grp;
  float sc = -3.0e38f;
  if (node < N) {
    const float2* hv = (const float2*)(h + (size_t)node * D_H);
    const float2* wv = (const float2*)watt;
    float acc = 0.f;
#pragma unroll
    for (int i = 0; i < 4; ++i) {
      float2 a = hv[i * 16 + l];
      float2 w = wv[i * 16 + l];
      acc = fmaf(a.x, w.x, acc);
      acc = fmaf(a.y, w.y, acc);
    }
#pragma unroll
    for (int off = 8; off > 0; off >>= 1) acc += __shfl_down(acc, off, 16);
    if (l == 0) {
      sc = acc + batt[0];
      scores[node] = sc;
    }
  }
  if (l == 0) smax[grp] = sc;
  __syncthreads();
  if (t == 0) {
    float m = smax[0];
    for (int i = 1; i < 16; ++i) m = fmaxf(m, smax[i]);
    partmax[blockIdx.x] = m;
  }
}

__global__ __launch_bounds__(256) void k_redmax(const float* __restrict__ partmax, int PB,
                                                float* __restrict__ red) {
  __shared__ float sm[256];
  int t = threadIdx.x;
  float m = -3.0e38f;
  for (int i = t; i < PB; i += 256) m = fmaxf(m, partmax[i]);
  sm[t] = m;
  __syncthreads();
  for (int off = 128; off > 0; off >>= 1) {
    if (t < off) sm[t] = fmaxf(sm[t], sm[t + off]);
    __syncthreads();
  }
  if (t == 0) {
    red[0] = sm[0];
    red[1] = 0.f;
  }
  for (int i = t; i < 1024; i += 256) red[2 + i] = 0.f;
}

__global__ __launch_bounds__(256) void k_pool(const float* __restrict__ h,
                                              const float* __restrict__ scores,
                                              const int* __restrict__ batch,
                                              float* __restrict__ red, int N, int nblocks) {
  __shared__ float pl[4][1024];
  __shared__ float zp[4];
  int t = threadIdx.x;
  int w = t >> 6, lane = t & 63;
  for (int i = lane; i < 1024; i += 64) pl[w][i] = 0.f;
  float M = red[0];
  float zacc = 0.f;
  const float2* hv = (const float2*)h;
  int stride = nblocks * 4;
  for (int node = blockIdx.x * 4 + w; node < N; node += stride) {
    float wgt = __expf(scores[node] - M);
    int b = batch[node];
    float2 v = hv[(size_t)node * 64 + lane];
    pl[w][b * 128 + lane * 2] += v.x * wgt;
    pl[w][b * 128 + lane * 2 + 1] += v.y * wgt;
    zacc += wgt;
  }
  if (lane == 0) zp[w] = zacc;
  __syncthreads();
  for (int i = t; i < 1024; i += 256) {
    float s = pl[0][i] + pl[1][i] + pl[2][i] + pl[3][i];
    atomicAdd(&red[2 + i], s);
  }
  if (t == 0) atomicAdd(&red[1], zp[0] + zp[1] + zp[2] + zp[3]);
}

__global__ __launch_bounds__(512) void k_out(const float* __restrict__ red,
                                             const float* __restrict__ Wout,
                                             const float* __restrict__ bout,
                                             float* __restrict__ out) {
  int t = threadIdx.x;
  int gIdx = t >> 6, o = t & 63;
  float invZ = 1.f / red[1];
  const float* p = red + 2 + gIdx * 128;
  const float* wr = Wout + (size_t)o * 128;
  float acc = 0.f;
  for (int k = 0; k < 128; ++k) acc = fmaf(p[k], wr[k], acc);
  out[gIdx * 64 + o] = acc * invZ + bout[o];
}

// ---------------- launcher ----------------

extern "C" void kernel_launch(void* const* d_in, const int* in_sizes, int n_in,
                              void* d_out, int out_size, void* d_ws, size_t ws_size,
                              hipStream_t stream) {
  const float* x     = (const float*)d_in[0];
  const int*   ei    = (const int*)d_in[1];
  const int*   batch = (const int*)d_in[2];
  const float* W_emb = (const float*)d_in[3];
  const float* b_emb = (const float*)d_in[4];
  const float* Wl0   = (const float*)d_in[5];
  const float* bl0   = (const float*)d_in[6];
  const float* Wr0   = (const float*)d_in[7];
  const float* Wl1   = (const float*)d_in[8];
  const float* bl1   = (const float*)d_in[9];
  const float* Wr1   = (const float*)d_in[10];
  const float* W_att = (const float*)d_in[11];
  const float* b_att = (const float*)d_in[12];
  const float* W_out = (const float*)d_in[13];
  const float* b_out = (const float*)d_in[14];
  float* out = (float*)d_out;

  const int DIN = 300;
  int N = in_sizes[0] / DIN;
  int E = in_sizes[1] / 2;
  int Npad = (N + 31) & ~31;

  char* wsp = (char*)d_ws;
  size_t off = 0;
  auto carve = [&](size_t bytes) -> void* {
    void* p = wsp + off;
    off += (bytes + 255) & ~(size_t)255;
    return p;
  };
  unsigned short* P = (unsigned short*)carve((size_t)Npad * 512);  // h pairs
  float*          U = (float*)carve((size_t)Npad * 512);           // A@Wl fp32
  float*          V = (float*)carve((size_t)Npad * 512);           // A@Wr fp32 / h2
  unsigned short* WembP = (unsigned short*)carve((size_t)128 * 640 * 2);
  unsigned short* WP0l  = (unsigned short*)carve((size_t)128 * 256 * 2);
  unsigned short* WP0r  = (unsigned short*)carve((size_t)128 * 256 * 2);
  unsigned short* WP1l  = (unsigned short*)carve((size_t)128 * 256 * 2);
  unsigned short* WP1r  = (unsigned short*)carve((size_t)128 * 256 * 2);
  int*   colA    = (int*)carve((size_t)E * 4);
  int*   row_ptr = (int*)carve((size_t)(N + 1) * 4);
  int*   deg     = (int*)carve((size_t)N * 4);
  int*   cnt     = (int*)carve((size_t)N * 4);
  float* scores  = (float*)carve((size_t)N * 4);
  int scoreBlocks = (N + 15) / 16;
  float* partmax = (float*)carve((size_t)scoreBlocks * 4);
  float* red     = (float*)carve((size_t)(2 + 1024) * 4);
  int scanBlocks = (N + 255) / 256;
  int*   partials = (int*)carve((size_t)scanBlocks * 4);

  const int* srcv = ei;
  const int* dstv = ei + E;

  hipMemsetAsync(deg, 0, (size_t)N * 4, stream);
  k_deg<<<1024, 256, 0, stream>>>(dstv, deg, E);
  k_wsplit<<<(128 * 320 + 4 * 16384 + 255) / 256, 256, 0, stream>>>(
      W_emb, Wl0, Wr0, Wl1, Wr1, WembP, WP0l, WP0r, WP1l, WP1r);
  k_partial<<<scanBlocks, 256, 0, stream>>>(deg, partials, N);
  k_scanpart<<<1, 256, 0, stream>>>(partials, scanBlocks, row_ptr, N);
  k_rowptr<<<scanBlocks, 256, 0, stream>>>(deg, partials, row_ptr, cnt, N);
  k_scatter<<<1024, 256, 0, stream>>>(srcv, dstv, cnt, colA, E);

  int gblocks = Npad / 32;
  // h0 pair
  k_emb<<<gblocks, 256, 0, stream>>>(x, WembP, b_emb, P, N);
  // conv0: U = h0@Wl0^T, V = h0@Wr0^T ; then h1 = relu(mean(U) + V + bl0) -> pair P
  k_conv<<<gblocks, 256, 0, stream>>>(P, WP0l, WP0r, U, V);
  k_aggfin<1><<<(N + 3) / 4, 256, 0, stream>>>(U, V, bl0, row_ptr, colA, P, N);
  // conv1: same; h2 fp32 in-place into V
  k_conv<<<gblocks, 256, 0, stream>>>(P, WP1l, WP1r, U, V);
  k_aggfin<0><<<(N + 3) / 4, 256, 0, stream>>>(U, V, bl1, row_ptr, colA, nullptr, N);

  const float* h2 = (const float*)V;
  k_score<<<scoreBlocks, 256, 0, stream>>>(h2, W_att, b_att, scores, partmax, N);
  k_redmax<<<1, 256, 0, stream>>>(partmax, scoreBlocks, red);
  k_pool<<<256, 256, 0, stream>>>(h2, scores, batch, red, N, 256);
  k_out<<<1, 512, 0, stream>>>(red, W_out, b_out, out);
}

// Round 7
// 344.914 us; speedup vs baseline: 1.2267x; 1.2267x over previous
//
#include <hip/hip_runtime.h>
#include <math.h>

#define D_H 128

typedef __attribute__((ext_vector_type(8))) __bf16 bf16x8;
typedef __attribute__((ext_vector_type(4))) float f32x4;

__device__ __forceinline__ void split_bf16(float v, unsigned short& hi, unsigned short& lo) {
  unsigned int u = __float_as_uint(v);
  hi = (unsigned short)(u >> 16);
  float l = v - __uint_as_float(u & 0xffff0000u);
  lo = (unsigned short)(__float_as_uint(l) >> 16);
}

// pack 8 floats -> hi bf16x8 + lo bf16x8 (truncation split)
__device__ __forceinline__ void pack_pair8(const float* xv, bf16x8& ah, bf16x8& al) {
  union { bf16x8 v; unsigned int u[4]; } H, L;
#pragma unroll
  for (int e = 0; e < 4; ++e) {
    unsigned int u0 = __float_as_uint(xv[2 * e]);
    unsigned int u1 = __float_as_uint(xv[2 * e + 1]);
    float l0 = xv[2 * e] - __uint_as_float(u0 & 0xffff0000u);
    float l1 = xv[2 * e + 1] - __uint_as_float(u1 & 0xffff0000u);
    H.u[e] = (u0 >> 16) | (u1 & 0xffff0000u);
    L.u[e] = (__float_as_uint(l0) >> 16) | (__float_as_uint(l1) & 0xffff0000u);
  }
  ah = H.v;
  al = L.v;
}

__device__ __forceinline__ void load_lds16(const void* g, void* l) {
  __builtin_amdgcn_global_load_lds((const __attribute__((address_space(1))) unsigned int*)g,
                                   (__attribute__((address_space(3))) unsigned int*)l,
                                   16, 0, 0);
}

// ---------------- graph build ----------------

__global__ void k_deg(const int* __restrict__ dstv, int* __restrict__ deg, int E) {
  for (int i = blockIdx.x * blockDim.x + threadIdx.x; i < E; i += gridDim.x * blockDim.x)
    atomicAdd(&deg[dstv[i]], 1);
}

__global__ __launch_bounds__(256) void k_partial(const int* __restrict__ deg,
                                                 int* __restrict__ partials, int N) {
  __shared__ int s[256];
  int t = threadIdx.x;
  int i = blockIdx.x * 256 + t;
  s[t] = (i < N) ? deg[i] : 0;
  __syncthreads();
  for (int off = 128; off > 0; off >>= 1) {
    if (t < off) s[t] += s[t + off];
    __syncthreads();
  }
  if (t == 0) partials[blockIdx.x] = s[0];
}

__global__ __launch_bounds__(256) void k_scanpart(int* __restrict__ partials, int NB,
                                                  int* __restrict__ row_ptr, int N) {
  __shared__ int s[256];
  int t = threadIdx.x;
  int v = (t < NB) ? partials[t] : 0;
  s[t] = v;
  __syncthreads();
  for (int off = 1; off < 256; off <<= 1) {
    int u = (t >= off) ? s[t - off] : 0;
    __syncthreads();
    s[t] += u;
    __syncthreads();
  }
  if (t < NB) partials[t] = s[t] - v;
  if (t == 255) row_ptr[N] = s[255];
}

__global__ __launch_bounds__(256) void k_rowptr(const int* __restrict__ deg,
                                                const int* __restrict__ partials,
                                                int* __restrict__ row_ptr,
                                                int* __restrict__ cnt, int N) {
  __shared__ int s[256];
  int t = threadIdx.x;
  int i = blockIdx.x * 256 + t;
  int v = (i < N) ? deg[i] : 0;
  s[t] = v;
  __syncthreads();
  for (int off = 1; off < 256; off <<= 1) {
    int u = (t >= off) ? s[t - off] : 0;
    __syncthreads();
    s[t] += u;
    __syncthreads();
  }
  if (i < N) {
    int ex = partials[blockIdx.x] + s[t] - v;
    row_ptr[i] = ex;
    cnt[i] = ex;
  }
}

__global__ void k_scatter(const int* __restrict__ srcv, const int* __restrict__ dstv,
                          int* __restrict__ cnt, int* __restrict__ col, int E) {
  for (int i = blockIdx.x * blockDim.x + threadIdx.x; i < E; i += gridDim.x * blockDim.x) {
    int d = dstv[i];
    int pos = atomicAdd(&cnt[d], 1);
    col[pos] = srcv[i];
  }
}

// ---------------- weight split + SWIZZLE (once) ----------------
// Pair layout per row (col o): [K hi | K lo] shorts, with byte offset within
// each region XOR'd by ((o&7)<<4)  -> T2 swizzle baked into global so LDS
// staging is a linear copy and ds_read applies the same XOR.
// emb row: 320hi|320lo (1280 B, K padded 300->320). conv row: 128hi|128lo (512 B).

__global__ __launch_bounds__(256) void k_wsplit(
    const float* __restrict__ Wemb, const float* __restrict__ Wl0,
    const float* __restrict__ Wr0, const float* __restrict__ Wl1,
    const float* __restrict__ Wr1, unsigned short* __restrict__ WembP,
    unsigned short* __restrict__ P0l, unsigned short* __restrict__ P0r,
    unsigned short* __restrict__ P1l, unsigned short* __restrict__ P1r) {
  int tid = blockIdx.x * 256 + threadIdx.x;
  const int EMB = 128 * 320;
  if (tid < EMB) {
    int o = tid / 320, k = tid - o * 320;
    float v = (k < 300) ? Wemb[o * 300 + k] : 0.f;
    unsigned short h, l;
    split_bf16(v, h, l);
    int sw = ((2 * k) ^ ((o & 7) << 4)) >> 1;
    WembP[o * 640 + sw] = h;
    WembP[o * 640 + 320 + sw] = l;
  } else if (tid < EMB + 4 * 16384) {
    int r = tid - EMB;
    int m = r >> 14;
    int i = r & 16383;
    int o = i >> 7, k = i & 127;
    const float* W = (m == 0) ? Wl0 : (m == 1) ? Wr0 : (m == 2) ? Wl1 : Wr1;
    unsigned short* P = (m == 0) ? P0l : (m == 1) ? P0r : (m == 2) ? P1l : P1r;
    unsigned short h, l;
    split_bf16(W[o * 128 + k], h, l);
    int sw = ((2 * k) ^ ((o & 7) << 4)) >> 1;
    P[o * 256 + sw] = h;
    P[o * 256 + 128 + sw] = l;
  }
}

// ---------------- emb GEMM: P = pair( x @ Wemb^T + b ) ----------------
// Block: 512 thr = 8 waves x 16 rows = 128 rows; blockIdx.y = col-half (64 cols).
// W-half staged to LDS in 2 K-chunks (k 0..191 and 192..319); A (x fp32) streamed
// direct to regs with depth-1 prefetch + in-register split. 3 barriers total.

__global__ __launch_bounds__(512, 4) void k_emb(const float* __restrict__ x,
                                                const unsigned short* __restrict__ Wp,
                                                const float* __restrict__ bias,
                                                unsigned short* __restrict__ P, int N) {
  __shared__ alignas(16) char sW[49152];
  int t = threadIdx.x, lane = t & 63, wave = t >> 6;
  int ch = blockIdx.y;
  int row0 = blockIdx.x * 128;
  int fr = lane & 15, q4 = lane >> 4;
  int X = (fr & 7) << 4;
  int row = row0 + wave * 16 + fr;
  if (row >= N) row = N - 1;
  const float* xrp = x + (size_t)row * 300;
  const char* Wbase = (const char*)Wp + (size_t)ch * 64 * 1280;
  f32x4 acc[4] = {};
  float xb[2][8];

  auto stage = [&](int CB, int HS, int kb, int nround) {
    for (int r = 0; r < nround; ++r) {
      int off = r * 8192 + wave * 1024;  // wave-uniform LDS dest
      int offl = off + lane * 16;
      int c = offl / CB;
      int w = offl - c * CB;
      const char* src = Wbase + (size_t)c * 1280 + (w < HS ? kb + w : 640 + kb + (w - HS));
      load_lds16(src, sW + off);
    }
  };
  auto loadx = [&](float* d, int c0) {
    if (c0 + 7 < 300) {
      float4 a = *(const float4*)(xrp + c0);
      float4 b = *(const float4*)(xrp + c0 + 4);
      d[0] = a.x; d[1] = a.y; d[2] = a.z; d[3] = a.w;
      d[4] = b.x; d[5] = b.y; d[6] = b.z; d[7] = b.w;
    } else {
#pragma unroll
      for (int e = 0; e < 8; ++e) d[e] = (c0 + e < 300) ? xrp[c0 + e] : 0.f;
    }
  };

  stage(768, 384, 0, 6);          // chunk0: k 0..191
  loadx(xb[0], q4 * 8);
  __syncthreads();

#pragma unroll
  for (int ks = 0; ks < 6; ++ks) {
    loadx(xb[(ks + 1) & 1], (ks + 1) * 32 + q4 * 8);
    bf16x8 bh[4], bl[4];
#pragma unroll
    for (int j = 0; j < 4; ++j) {
      int c64 = j * 16 + fr;
      int ko = (ks * 64 + q4 * 16) ^ X;
      bh[j] = *(const bf16x8*)(sW + c64 * 768 + ko);
      bl[j] = *(const bf16x8*)(sW + c64 * 768 + 384 + ko);
    }
    bf16x8 ah, al;
    pack_pair8(xb[ks & 1], ah, al);
#pragma unroll
    for (int j = 0; j < 4; ++j) {
      acc[j] = __builtin_amdgcn_mfma_f32_16x16x32_bf16(ah, bh[j], acc[j], 0, 0, 0);
      acc[j] = __builtin_amdgcn_mfma_f32_16x16x32_bf16(ah, bl[j], acc[j], 0, 0, 0);
      acc[j] = __builtin_amdgcn_mfma_f32_16x16x32_bf16(al, bh[j], acc[j], 0, 0, 0);
    }
  }
  __syncthreads();                 // all waves done with chunk0
  stage(512, 256, 384, 4);         // chunk1: k 192..319
  __syncthreads();

#pragma unroll
  for (int ks2 = 0; ks2 < 4; ++ks2) {
    int ks = 6 + ks2;
    if (ks < 9) loadx(xb[(ks + 1) & 1], (ks + 1) * 32 + q4 * 8);
    bf16x8 bh[4], bl[4];
#pragma unroll
    for (int j = 0; j < 4; ++j) {
      int c64 = j * 16 + fr;
      int ko = (ks2 * 64 + q4 * 16) ^ X;
      bh[j] = *(const bf16x8*)(sW + c64 * 512 + ko);
      bl[j] = *(const bf16x8*)(sW + c64 * 512 + 256 + ko);
    }
    bf16x8 ah, al;
    pack_pair8(xb[ks & 1], ah, al);
#pragma unroll
    for (int j = 0; j < 4; ++j) {
      acc[j] = __builtin_amdgcn_mfma_f32_16x16x32_bf16(ah, bh[j], acc[j], 0, 0, 0);
      acc[j] = __builtin_amdgcn_mfma_f32_16x16x32_bf16(ah, bl[j], acc[j], 0, 0, 0);
      acc[j] = __builtin_amdgcn_mfma_f32_16x16x32_bf16(al, bh[j], acc[j], 0, 0, 0);
    }
  }
  __syncthreads();

  // epilogue: reuse sW as f32 [128][66] transpose buffer -> packed pair stores
  float* T = (float*)sW;
#pragma unroll
  for (int j = 0; j < 4; ++j) {
    float b = bias[ch * 64 + j * 16 + fr];
#pragma unroll
    for (int rg = 0; rg < 4; ++rg)
      T[(wave * 16 + q4 * 4 + rg) * 66 + j * 16 + fr] = acc[j][rg] + b;
  }
  __syncthreads();
  int rr = t >> 2, q = t & 3;
  float vals[16];
#pragma unroll
  for (int c = 0; c < 16; ++c) vals[c] = T[rr * 66 + q * 16 + c];
  unsigned int hu[8], lu[8];
#pragma unroll
  for (int e = 0; e < 8; ++e) {
    unsigned int u0 = __float_as_uint(vals[2 * e]);
    unsigned int u1 = __float_as_uint(vals[2 * e + 1]);
    float l0 = vals[2 * e] - __uint_as_float(u0 & 0xffff0000u);
    float l1 = vals[2 * e + 1] - __uint_as_float(u1 & 0xffff0000u);
    hu[e] = (u0 >> 16) | (u1 & 0xffff0000u);
    lu[e] = (__float_as_uint(l0) >> 16) | (__float_as_uint(l1) & 0xffff0000u);
  }
  char* rowp = (char*)P + (size_t)(row0 + rr) * 512 + ch * 128;
  *(uint4*)(rowp + q * 32) = make_uint4(hu[0], hu[1], hu[2], hu[3]);
  *(uint4*)(rowp + q * 32 + 16) = make_uint4(hu[4], hu[5], hu[6], hu[7]);
  *(uint4*)(rowp + 256 + q * 32) = make_uint4(lu[0], lu[1], lu[2], lu[3]);
  *(uint4*)(rowp + 256 + q * 32 + 16) = make_uint4(lu[4], lu[5], lu[6], lu[7]);
}

// ---------------- conv GEMM: OUT = A @ W^T (fp32), W resident in LDS ----------------
// Block: 512 thr = 8 waves = 4 row-slices x 2 col-halves; 128 rows/block.
// blockIdx.y = om (0: U=A@Wl, 1: V=A@Wr). Full W-pair (64 KB) staged once,
// 1 barrier, then barrier-free K loop (4 steps) with depth-1 A prefetch.

__global__ __launch_bounds__(512, 4) void k_conv(const unsigned short* __restrict__ Ap,
                                                 const unsigned short* __restrict__ Wl,
                                                 const unsigned short* __restrict__ Wr,
                                                 float* __restrict__ U,
                                                 float* __restrict__ V) {
  __shared__ alignas(16) char sW[65536];
  int t = threadIdx.x, lane = t & 63, wave = t >> 6;
  int wr = wave >> 1, wc = wave & 1;
  int om = blockIdx.y;
  const char* Wg = (const char*)(om ? Wr : Wl);
  float* OUT = om ? V : U;
  int row0 = blockIdx.x * 128;
  int fr = lane & 15, q4 = lane >> 4;
  int X = (fr & 7) << 4;

  // stage 64 KB W (linear copy; swizzle already in global layout)
  for (int r = 0; r < 8; ++r) {
    int off = r * 8192 + wave * 1024;
    load_lds16(Wg + off + lane * 16, sW + off);
  }

  const char* a0 = (const char*)Ap + (size_t)(row0 + wr * 32 + fr) * 512 + q4 * 16;
  const char* a1 = a0 + 16 * 512;
  bf16x8 ah[2][2], al[2][2];
  ah[0][0] = *(const bf16x8*)a0;
  al[0][0] = *(const bf16x8*)(a0 + 256);
  ah[0][1] = *(const bf16x8*)a1;
  al[0][1] = *(const bf16x8*)(a1 + 256);

  f32x4 acc[2][4] = {};
  __syncthreads();

#pragma unroll
  for (int ks = 0; ks < 4; ++ks) {
    if (ks < 3) {
      int nb = (ks + 1) * 64;
      ah[(ks + 1) & 1][0] = *(const bf16x8*)(a0 + nb);
      al[(ks + 1) & 1][0] = *(const bf16x8*)(a0 + nb + 256);
      ah[(ks + 1) & 1][1] = *(const bf16x8*)(a1 + nb);
      al[(ks + 1) & 1][1] = *(const bf16x8*)(a1 + nb + 256);
    }
#pragma unroll
    for (int j = 0; j < 4; ++j) {
      int c = wc * 64 + j * 16 + fr;
      int ko = (ks * 64 + q4 * 16) ^ X;
      bf16x8 bh = *(const bf16x8*)(sW + c * 512 + ko);
      bf16x8 bl = *(const bf16x8*)(sW + c * 512 + 256 + ko);
#pragma unroll
      for (int i = 0; i < 2; ++i) {
        acc[i][j] = __builtin_amdgcn_mfma_f32_16x16x32_bf16(ah[ks & 1][i], bh, acc[i][j], 0, 0, 0);
        acc[i][j] = __builtin_amdgcn_mfma_f32_16x16x32_bf16(ah[ks & 1][i], bl, acc[i][j], 0, 0, 0);
        acc[i][j] = __builtin_amdgcn_mfma_f32_16x16x32_bf16(al[ks & 1][i], bh, acc[i][j], 0, 0, 0);
      }
    }
  }

#pragma unroll
  for (int i = 0; i < 2; ++i)
#pragma unroll
    for (int j = 0; j < 4; ++j)
#pragma unroll
      for (int rg = 0; rg < 4; ++rg)
        OUT[(size_t)(row0 + wr * 32 + i * 16 + q4 * 4 + rg) * D_H + wc * 64 + j * 16 + fr] =
            acc[i][j][rg];
}

// ---------------- fused aggregate + epilogue ----------------
// h' = relu( mean-gather(U) + V + bias ); OUTP=1 -> pair out, OUTP=0 -> fp32
// in-place into V. One wave per node, float2 per lane.

template <int OUTP>
__global__ __launch_bounds__(256) void k_aggfin(const float* __restrict__ U,
                                                float* __restrict__ V,
                                                const float* __restrict__ bias,
                                                const int* __restrict__ row_ptr,
                                                const int* __restrict__ col,
                                                unsigned short* __restrict__ Hp, int N) {
  int wid = blockIdx.x * 4 + (threadIdx.x >> 6);
  if (wid >= N) return;
  int lane = threadIdx.x & 63;
  const float2* uv = (const float2*)U;
  int e0 = row_ptr[wid], e1 = row_ptr[wid + 1];
  float ax = 0.f, ay = 0.f;
  int e = e0;
  for (; e + 4 <= e1; e += 4) {
    int s0 = col[e], s1 = col[e + 1], s2 = col[e + 2], s3 = col[e + 3];
    float2 v0 = uv[(size_t)s0 * 64 + lane];
    float2 v1 = uv[(size_t)s1 * 64 + lane];
    float2 v2 = uv[(size_t)s2 * 64 + lane];
    float2 v3 = uv[(size_t)s3 * 64 + lane];
    ax += v0.x + v1.x + v2.x + v3.x;
    ay += v0.y + v1.y + v2.y + v3.y;
  }
  for (; e < e1; ++e) {
    float2 v = uv[(size_t)col[e] * 64 + lane];
    ax += v.x;
    ay += v.y;
  }
  float inv = 1.f / fmaxf((float)(e1 - e0), 1.f);
  float2 vv = ((const float2*)V)[(size_t)wid * 64 + lane];
  float2 bb = ((const float2*)bias)[lane];
  float ox = fmaxf(ax * inv + vv.x + bb.x, 0.f);
  float oy = fmaxf(ay * inv + vv.y + bb.y, 0.f);
  if (OUTP) {
    unsigned short hx, lx, hy, ly;
    split_bf16(ox, hx, lx);
    split_bf16(oy, hy, ly);
    ((unsigned int*)((char*)Hp + (size_t)wid * 512))[lane] =
        (unsigned int)hx | ((unsigned int)hy << 16);
    ((unsigned int*)((char*)Hp + (size_t)wid * 512 + 256))[lane] =
        (unsigned int)lx | ((unsigned int)ly << 16);
  } else {
    ((float2*)V)[(size_t)wid * 64 + lane] = make_float2(ox, oy);
  }
}

// ---------------- attention readout ----------------

__global__ __launch_bounds__(256) void k_score(const float* __restrict__ h,
                                               const float* __restrict__ watt,
                                               const float* __restrict__ batt,
                                               float* __restrict__ scores,
                                               float* __restrict__ partmax, int N) {
  __shared__ float smax[16];
  int t = threadIdx.x;
  int grp = t >> 4, l = t & 15;
  int node = blockIdx.x * 16 + grp;
  float sc = -3.0e38f;
  if (node < N) {
    const float2* hv = (const float2*)(h + (size_t)node * D_H);
    const float2* wv = (const float2*)watt;
    float acc = 0.f;
#pragma unroll
    for (int i = 0; i < 4; ++i) {
      float2 a = hv[i * 16 + l];
      float2 w = wv[i * 16 + l];
      acc = fmaf(a.x, w.x, acc);
      acc = fmaf(a.y, w.y, acc);
    }
#pragma unroll
    for (int off = 8; off > 0; off >>= 1) acc += __shfl_down(acc, off, 16);
    if (l == 0) {
      sc = acc + batt[0];
      scores[node] = sc;
    }
  }
  if (l == 0) smax[grp] = sc;
  __syncthreads();
  if (t == 0) {
    float m = smax[0];
    for (int i = 1; i < 16; ++i) m = fmaxf(m, smax[i]);
    partmax[blockIdx.x] = m;
  }
}

__global__ __launch_bounds__(256) void k_redmax(const float* __restrict__ partmax, int PB,
                                                float* __restrict__ red) {
  __shared__ float sm[256];
  int t = threadIdx.x;
  float m = -3.0e38f;
  for (int i = t; i < PB; i += 256) m = fmaxf(m, partmax[i]);
  sm[t] = m;
  __syncthreads();
  for (int off = 128; off > 0; off >>= 1) {
    if (t < off) sm[t] = fmaxf(sm[t], sm[t + off]);
    __syncthreads();
  }
  if (t == 0) {
    red[0] = sm[0];
    red[1] = 0.f;
  }
  for (int i = t; i < 1024; i += 256) red[2 + i] = 0.f;
}

__global__ __launch_bounds__(256) void k_pool(const float* __restrict__ h,
                                              const float* __restrict__ scores,
                                              const int* __restrict__ batch,
                                              float* __restrict__ red, int N, int nblocks) {
  __shared__ float pl[4][1024];
  __shared__ float zp[4];
  int t = threadIdx.x;
  int w = t >> 6, lane = t & 63;
  for (int i = lane; i < 1024; i += 64) pl[w][i] = 0.f;
  float M = red[0];
  float zacc = 0.f;
  const float2* hv = (const float2*)h;
  int stride = nblocks * 4;
  for (int node = blockIdx.x * 4 + w; node < N; node += stride) {
    float wgt = __expf(scores[node] - M);
    int b = batch[node];
    float2 v = hv[(size_t)node * 64 + lane];
    pl[w][b * 128 + lane * 2] += v.x * wgt;
    pl[w][b * 128 + lane * 2 + 1] += v.y * wgt;
    zacc += wgt;
  }
  if (lane == 0) zp[w] = zacc;
  __syncthreads();
  for (int i = t; i < 1024; i += 256) {
    float s = pl[0][i] + pl[1][i] + pl[2][i] + pl[3][i];
    atomicAdd(&red[2 + i], s);
  }
  if (t == 0) atomicAdd(&red[1], zp[0] + zp[1] + zp[2] + zp[3]);
}

__global__ __launch_bounds__(512) void k_out(const float* __restrict__ red,
                                             const float* __restrict__ Wout,
                                             const float* __restrict__ bout,
                                             float* __restrict__ out) {
  int t = threadIdx.x;
  int gIdx = t >> 6, o = t & 63;
  float invZ = 1.f / red[1];
  const float* p = red + 2 + gIdx * 128;
  const float* wr = Wout + (size_t)o * 128;
  float acc = 0.f;
  for (int k = 0; k < 128; ++k) acc = fmaf(p[k], wr[k], acc);
  out[gIdx * 64 + o] = acc * invZ + bout[o];
}

// ---------------- launcher ----------------

extern "C" void kernel_launch(void* const* d_in, const int* in_sizes, int n_in,
                              void* d_out, int out_size, void* d_ws, size_t ws_size,
                              hipStream_t stream) {
  const float* x     = (const float*)d_in[0];
  const int*   ei    = (const int*)d_in[1];
  const int*   batch = (const int*)d_in[2];
  const float* W_emb = (const float*)d_in[3];
  const float* b_emb = (const float*)d_in[4];
  const float* Wl0   = (const float*)d_in[5];
  const float* bl0   = (const float*)d_in[6];
  const float* Wr0   = (const float*)d_in[7];
  const float* Wl1   = (const float*)d_in[8];
  const float* bl1   = (const float*)d_in[9];
  const float* Wr1   = (const float*)d_in[10];
  const float* W_att = (const float*)d_in[11];
  const float* b_att = (const float*)d_in[12];
  const float* W_out = (const float*)d_in[13];
  const float* b_out = (const float*)d_in[14];
  float* out = (float*)d_out;

  const int DIN = 300;
  int N = in_sizes[0] / DIN;
  int E = in_sizes[1] / 2;
  int Npad = (N + 127) & ~127;

  char* wsp = (char*)d_ws;
  size_t off = 0;
  auto carve = [&](size_t bytes) -> void* {
    void* p = wsp + off;
    off += (bytes + 255) & ~(size_t)255;
    return p;
  };
  unsigned short* P = (unsigned short*)carve((size_t)Npad * 512);  // h pairs
  float*          U = (float*)carve((size_t)Npad * 512);           // A@Wl fp32
  float*          V = (float*)carve((size_t)Npad * 512);           // A@Wr fp32 / h2
  unsigned short* WembP = (unsigned short*)carve((size_t)128 * 640 * 2);
  unsigned short* WP0l  = (unsigned short*)carve((size_t)128 * 256 * 2);
  unsigned short* WP0r  = (unsigned short*)carve((size_t)128 * 256 * 2);
  unsigned short* WP1l  = (unsigned short*)carve((size_t)128 * 256 * 2);
  unsigned short* WP1r  = (unsigned short*)carve((size_t)128 * 256 * 2);
  int*   colA    = (int*)carve((size_t)E * 4);
  int*   row_ptr = (int*)carve((size_t)(N + 1) * 4);
  int*   deg     = (int*)carve((size_t)N * 4);
  int*   cnt     = (int*)carve((size_t)N * 4);
  float* scores  = (float*)carve((size_t)N * 4);
  int scoreBlocks = (N + 15) / 16;
  float* partmax = (float*)carve((size_t)scoreBlocks * 4);
  float* red     = (float*)carve((size_t)(2 + 1024) * 4);
  int scanBlocks = (N + 255) / 256;
  int*   partials = (int*)carve((size_t)scanBlocks * 4);

  const int* srcv = ei;
  const int* dstv = ei + E;

  hipMemsetAsync(deg, 0, (size_t)N * 4, stream);
  k_deg<<<1024, 256, 0, stream>>>(dstv, deg, E);
  k_wsplit<<<(128 * 320 + 4 * 16384 + 255) / 256, 256, 0, stream>>>(
      W_emb, Wl0, Wr0, Wl1, Wr1, WembP, WP0l, WP0r, WP1l, WP1r);
  k_partial<<<scanBlocks, 256, 0, stream>>>(deg, partials, N);
  k_scanpart<<<1, 256, 0, stream>>>(partials, scanBlocks, row_ptr, N);
  k_rowptr<<<scanBlocks, 256, 0, stream>>>(deg, partials, row_ptr, cnt, N);
  k_scatter<<<1024, 256, 0, stream>>>(srcv, dstv, cnt, colA, E);

  dim3 gemb(Npad / 128, 2);
  k_emb<<<gemb, 512, 0, stream>>>(x, WembP, b_emb, P, N);

  dim3 gconv(Npad / 128, 2);
  // conv0: U = h0@Wl0^T, V = h0@Wr0^T ; then h1 = relu(mean(U)+V+bl0) -> pair P
  k_conv<<<gconv, 512, 0, stream>>>(P, WP0l, WP0r, U, V);
  k_aggfin<1><<<(N + 3) / 4, 256, 0, stream>>>(U, V, bl0, row_ptr, colA, P, N);
  // conv1: same; h2 fp32 in-place into V
  k_conv<<<gconv, 512, 0, stream>>>(P, WP1l, WP1r, U, V);
  k_aggfin<0><<<(N + 3) / 4, 256, 0, stream>>>(U, V, bl1, row_ptr, colA, nullptr, N);

  const float* h2 = (const float*)V;
  k_score<<<scoreBlocks, 256, 0, stream>>>(h2, W_att, b_att, scores, partmax, N);
  k_redmax<<<1, 256, 0, stream>>>(partmax, scoreBlocks, red);
  k_pool<<<256, 256, 0, stream>>>(h2, scores, batch, red, N, 256);
  k_out<<<1, 512, 0, stream>>>(red, W_out, b_out, out);
}

// Round 8
// 321.166 us; speedup vs baseline: 1.3174x; 1.0739x over previous
//
#include <hip/hip_runtime.h>
#include <math.h>

#define D_H 128

typedef __attribute__((ext_vector_type(8))) __bf16 bf16x8;
typedef __attribute__((ext_vector_type(4))) float f32x4;

__device__ __forceinline__ void split_bf16(float v, unsigned short& hi, unsigned short& lo) {
  unsigned int u = __float_as_uint(v);
  hi = (unsigned short)(u >> 16);
  float l = v - __uint_as_float(u & 0xffff0000u);
  lo = (unsigned short)(__float_as_uint(l) >> 16);
}

__device__ __forceinline__ float blo(unsigned int u) { return __uint_as_float(u << 16); }
__device__ __forceinline__ float bhi(unsigned int u) { return __uint_as_float(u & 0xffff0000u); }

// round-to-nearest-even f32 -> bf16 (packed pair of two floats)
__device__ __forceinline__ unsigned int pack_bf16rn(float a, float b) {
  unsigned int ua = __float_as_uint(a);
  unsigned int ub = __float_as_uint(b);
  ua += 0x7fffu + ((ua >> 16) & 1);
  ub += 0x7fffu + ((ub >> 16) & 1);
  return (ua >> 16) | (ub & 0xffff0000u);
}

// pack 8 floats -> hi bf16x8 + lo bf16x8 (truncation split)
__device__ __forceinline__ void pack_pair8(const float* xv, bf16x8& ah, bf16x8& al) {
  union { bf16x8 v; unsigned int u[4]; } H, L;
#pragma unroll
  for (int e = 0; e < 4; ++e) {
    unsigned int u0 = __float_as_uint(xv[2 * e]);
    unsigned int u1 = __float_as_uint(xv[2 * e + 1]);
    float l0 = xv[2 * e] - __uint_as_float(u0 & 0xffff0000u);
    float l1 = xv[2 * e + 1] - __uint_as_float(u1 & 0xffff0000u);
    H.u[e] = (u0 >> 16) | (u1 & 0xffff0000u);
    L.u[e] = (__float_as_uint(l0) >> 16) | (__float_as_uint(l1) & 0xffff0000u);
  }
  ah = H.v;
  al = L.v;
}

__device__ __forceinline__ void load_lds16(const void* g, void* l) {
  __builtin_amdgcn_global_load_lds((const __attribute__((address_space(1))) unsigned int*)g,
                                   (__attribute__((address_space(3))) unsigned int*)l,
                                   16, 0, 0);
}

// ---------------- graph build ----------------

__global__ void k_deg(const int* __restrict__ dstv, int* __restrict__ deg, int E) {
  for (int i = blockIdx.x * blockDim.x + threadIdx.x; i < E; i += gridDim.x * blockDim.x)
    atomicAdd(&deg[dstv[i]], 1);
}

__global__ __launch_bounds__(256) void k_partial(const int* __restrict__ deg,
                                                 int* __restrict__ partials, int N) {
  __shared__ int s[256];
  int t = threadIdx.x;
  int i = blockIdx.x * 256 + t;
  s[t] = (i < N) ? deg[i] : 0;
  __syncthreads();
  for (int off = 128; off > 0; off >>= 1) {
    if (t < off) s[t] += s[t + off];
    __syncthreads();
  }
  if (t == 0) partials[blockIdx.x] = s[0];
}

__global__ __launch_bounds__(256) void k_scanpart(int* __restrict__ partials, int NB,
                                                  int* __restrict__ row_ptr, int N) {
  __shared__ int s[256];
  int t = threadIdx.x;
  int v = (t < NB) ? partials[t] : 0;
  s[t] = v;
  __syncthreads();
  for (int off = 1; off < 256; off <<= 1) {
    int u = (t >= off) ? s[t - off] : 0;
    __syncthreads();
    s[t] += u;
    __syncthreads();
  }
  if (t < NB) partials[t] = s[t] - v;
  if (t == 255) row_ptr[N] = s[255];
}

__global__ __launch_bounds__(256) void k_rowptr(const int* __restrict__ deg,
                                                const int* __restrict__ partials,
                                                int* __restrict__ row_ptr,
                                                int* __restrict__ cnt, int N) {
  __shared__ int s[256];
  int t = threadIdx.x;
  int i = blockIdx.x * 256 + t;
  int v = (i < N) ? deg[i] : 0;
  s[t] = v;
  __syncthreads();
  for (int off = 1; off < 256; off <<= 1) {
    int u = (t >= off) ? s[t - off] : 0;
    __syncthreads();
    s[t] += u;
    __syncthreads();
  }
  if (i < N) {
    int ex = partials[blockIdx.x] + s[t] - v;
    row_ptr[i] = ex;
    cnt[i] = ex;
  }
}

__global__ void k_scatter(const int* __restrict__ srcv, const int* __restrict__ dstv,
                          int* __restrict__ cnt, int* __restrict__ col, int E) {
  for (int i = blockIdx.x * blockDim.x + threadIdx.x; i < E; i += gridDim.x * blockDim.x) {
    int d = dstv[i];
    int pos = atomicAdd(&cnt[d], 1);
    col[pos] = srcv[i];
  }
}

// ---------------- weight split + SWIZZLE (once) ----------------

__global__ __launch_bounds__(256) void k_wsplit(
    const float* __restrict__ Wemb, const float* __restrict__ Wl0,
    const float* __restrict__ Wr0, const float* __restrict__ Wl1,
    const float* __restrict__ Wr1, unsigned short* __restrict__ WembP,
    unsigned short* __restrict__ P0l, unsigned short* __restrict__ P0r,
    unsigned short* __restrict__ P1l, unsigned short* __restrict__ P1r) {
  int tid = blockIdx.x * 256 + threadIdx.x;
  const int EMB = 128 * 320;
  if (tid < EMB) {
    int o = tid / 320, k = tid - o * 320;
    float v = (k < 300) ? Wemb[o * 300 + k] : 0.f;
    unsigned short h, l;
    split_bf16(v, h, l);
    int sw = ((2 * k) ^ ((o & 7) << 4)) >> 1;
    WembP[o * 640 + sw] = h;
    WembP[o * 640 + 320 + sw] = l;
  } else if (tid < EMB + 4 * 16384) {
    int r = tid - EMB;
    int m = r >> 14;
    int i = r & 16383;
    int o = i >> 7, k = i & 127;
    const float* W = (m == 0) ? Wl0 : (m == 1) ? Wr0 : (m == 2) ? Wl1 : Wr1;
    unsigned short* P = (m == 0) ? P0l : (m == 1) ? P0r : (m == 2) ? P1l : P1r;
    unsigned short h, l;
    split_bf16(W[o * 128 + k], h, l);
    int sw = ((2 * k) ^ ((o & 7) << 4)) >> 1;
    P[o * 256 + sw] = h;
    P[o * 256 + 128 + sw] = l;
  }
}

// ---------------- emb GEMM: P = pair( x @ Wemb^T + b ) ----------------

__global__ __launch_bounds__(512, 4) void k_emb(const float* __restrict__ x,
                                                const unsigned short* __restrict__ Wp,
                                                const float* __restrict__ bias,
                                                unsigned short* __restrict__ P, int N) {
  __shared__ alignas(16) char sW[49152];
  int t = threadIdx.x, lane = t & 63, wave = t >> 6;
  int ch = blockIdx.y;
  int row0 = blockIdx.x * 128;
  int fr = lane & 15, q4 = lane >> 4;
  int X = (fr & 7) << 4;
  int row = row0 + wave * 16 + fr;
  if (row >= N) row = N - 1;
  const float* xrp = x + (size_t)row * 300;
  const char* Wbase = (const char*)Wp + (size_t)ch * 64 * 1280;
  f32x4 acc[4] = {};
  float xb[2][8];

  auto stage = [&](int CB, int HS, int kb, int nround) {
    for (int r = 0; r < nround; ++r) {
      int off = r * 8192 + wave * 1024;
      int offl = off + lane * 16;
      int c = offl / CB;
      int w = offl - c * CB;
      const char* src = Wbase + (size_t)c * 1280 + (w < HS ? kb + w : 640 + kb + (w - HS));
      load_lds16(src, sW + off);
    }
  };
  auto loadx = [&](float* d, int c0) {
    if (c0 + 7 < 300) {
      float4 a = *(const float4*)(xrp + c0);
      float4 b = *(const float4*)(xrp + c0 + 4);
      d[0] = a.x; d[1] = a.y; d[2] = a.z; d[3] = a.w;
      d[4] = b.x; d[5] = b.y; d[6] = b.z; d[7] = b.w;
    } else {
#pragma unroll
      for (int e = 0; e < 8; ++e) d[e] = (c0 + e < 300) ? xrp[c0 + e] : 0.f;
    }
  };

  stage(768, 384, 0, 6);
  loadx(xb[0], q4 * 8);
  __syncthreads();

#pragma unroll
  for (int ks = 0; ks < 6; ++ks) {
    loadx(xb[(ks + 1) & 1], (ks + 1) * 32 + q4 * 8);
    bf16x8 bh[4], bl[4];
#pragma unroll
    for (int j = 0; j < 4; ++j) {
      int c64 = j * 16 + fr;
      int ko = (ks * 64 + q4 * 16) ^ X;
      bh[j] = *(const bf16x8*)(sW + c64 * 768 + ko);
      bl[j] = *(const bf16x8*)(sW + c64 * 768 + 384 + ko);
    }
    bf16x8 ah, al;
    pack_pair8(xb[ks & 1], ah, al);
#pragma unroll
    for (int j = 0; j < 4; ++j) {
      acc[j] = __builtin_amdgcn_mfma_f32_16x16x32_bf16(ah, bh[j], acc[j], 0, 0, 0);
      acc[j] = __builtin_amdgcn_mfma_f32_16x16x32_bf16(ah, bl[j], acc[j], 0, 0, 0);
      acc[j] = __builtin_amdgcn_mfma_f32_16x16x32_bf16(al, bh[j], acc[j], 0, 0, 0);
    }
  }
  __syncthreads();
  stage(512, 256, 384, 4);
  __syncthreads();

#pragma unroll
  for (int ks2 = 0; ks2 < 4; ++ks2) {
    int ks = 6 + ks2;
    if (ks < 9) loadx(xb[(ks + 1) & 1], (ks + 1) * 32 + q4 * 8);
    bf16x8 bh[4], bl[4];
#pragma unroll
    for (int j = 0; j < 4; ++j) {
      int c64 = j * 16 + fr;
      int ko = (ks2 * 64 + q4 * 16) ^ X;
      bh[j] = *(const bf16x8*)(sW + c64 * 512 + ko);
      bl[j] = *(const bf16x8*)(sW + c64 * 512 + 256 + ko);
    }
    bf16x8 ah, al;
    pack_pair8(xb[ks & 1], ah, al);
#pragma unroll
    for (int j = 0; j < 4; ++j) {
      acc[j] = __builtin_amdgcn_mfma_f32_16x16x32_bf16(ah, bh[j], acc[j], 0, 0, 0);
      acc[j] = __builtin_amdgcn_mfma_f32_16x16x32_bf16(ah, bl[j], acc[j], 0, 0, 0);
      acc[j] = __builtin_amdgcn_mfma_f32_16x16x32_bf16(al, bh[j], acc[j], 0, 0, 0);
    }
  }
  __syncthreads();

  float* T = (float*)sW;
#pragma unroll
  for (int j = 0; j < 4; ++j) {
    float b = bias[ch * 64 + j * 16 + fr];
#pragma unroll
    for (int rg = 0; rg < 4; ++rg)
      T[(wave * 16 + q4 * 4 + rg) * 66 + j * 16 + fr] = acc[j][rg] + b;
  }
  __syncthreads();
  int rr = t >> 2, q = t & 3;
  float vals[16];
#pragma unroll
  for (int c = 0; c < 16; ++c) vals[c] = T[rr * 66 + q * 16 + c];
  unsigned int hu[8], lu[8];
#pragma unroll
  for (int e = 0; e < 8; ++e) {
    unsigned int u0 = __float_as_uint(vals[2 * e]);
    unsigned int u1 = __float_as_uint(vals[2 * e + 1]);
    float l0 = vals[2 * e] - __uint_as_float(u0 & 0xffff0000u);
    float l1 = vals[2 * e + 1] - __uint_as_float(u1 & 0xffff0000u);
    hu[e] = (u0 >> 16) | (u1 & 0xffff0000u);
    lu[e] = (__float_as_uint(l0) >> 16) | (__float_as_uint(l1) & 0xffff0000u);
  }
  char* rowp = (char*)P + (size_t)(row0 + rr) * 512 + ch * 128;
  *(uint4*)(rowp + q * 32) = make_uint4(hu[0], hu[1], hu[2], hu[3]);
  *(uint4*)(rowp + q * 32 + 16) = make_uint4(hu[4], hu[5], hu[6], hu[7]);
  *(uint4*)(rowp + 256 + q * 32) = make_uint4(lu[0], lu[1], lu[2], lu[3]);
  *(uint4*)(rowp + 256 + q * 32 + 16) = make_uint4(lu[4], lu[5], lu[6], lu[7]);
}

// ---------------- conv GEMM ----------------
// blockIdx.y==0: U = A@Wl^T as PACKED BF16 [row][128 ushort] via LDS transpose.
// blockIdx.y==1: V = A@Wr^T as fp32 direct stores.

__global__ __launch_bounds__(512, 4) void k_conv(const unsigned short* __restrict__ Ap,
                                                 const unsigned short* __restrict__ Wl,
                                                 const unsigned short* __restrict__ Wr,
                                                 unsigned short* __restrict__ Ub,
                                                 float* __restrict__ V) {
  __shared__ alignas(16) char sW[65536];
  int t = threadIdx.x, lane = t & 63, wave = t >> 6;
  int wr = wave >> 1, wc = wave & 1;
  int om = blockIdx.y;
  const char* Wg = (const char*)(om ? Wr : Wl);
  int row0 = blockIdx.x * 128;
  int fr = lane & 15, q4 = lane >> 4;
  int X = (fr & 7) << 4;

  for (int r = 0; r < 8; ++r) {
    int off = r * 8192 + wave * 1024;
    load_lds16(Wg + off + lane * 16, sW + off);
  }

  const char* a0 = (const char*)Ap + (size_t)(row0 + wr * 32 + fr) * 512 + q4 * 16;
  const char* a1 = a0 + 16 * 512;
  bf16x8 ah[2][2], al[2][2];
  ah[0][0] = *(const bf16x8*)a0;
  al[0][0] = *(const bf16x8*)(a0 + 256);
  ah[0][1] = *(const bf16x8*)a1;
  al[0][1] = *(const bf16x8*)(a1 + 256);

  f32x4 acc[2][4] = {};
  __syncthreads();

#pragma unroll
  for (int ks = 0; ks < 4; ++ks) {
    if (ks < 3) {
      int nb = (ks + 1) * 64;
      ah[(ks + 1) & 1][0] = *(const bf16x8*)(a0 + nb);
      al[(ks + 1) & 1][0] = *(const bf16x8*)(a0 + nb + 256);
      ah[(ks + 1) & 1][1] = *(const bf16x8*)(a1 + nb);
      al[(ks + 1) & 1][1] = *(const bf16x8*)(a1 + nb + 256);
    }
#pragma unroll
    for (int j = 0; j < 4; ++j) {
      int c = wc * 64 + j * 16 + fr;
      int ko = (ks * 64 + q4 * 16) ^ X;
      bf16x8 bh = *(const bf16x8*)(sW + c * 512 + ko);
      bf16x8 bl = *(const bf16x8*)(sW + c * 512 + 256 + ko);
#pragma unroll
      for (int i = 0; i < 2; ++i) {
        acc[i][j] = __builtin_amdgcn_mfma_f32_16x16x32_bf16(ah[ks & 1][i], bh, acc[i][j], 0, 0, 0);
        acc[i][j] = __builtin_amdgcn_mfma_f32_16x16x32_bf16(ah[ks & 1][i], bl, acc[i][j], 0, 0, 0);
        acc[i][j] = __builtin_amdgcn_mfma_f32_16x16x32_bf16(al[ks & 1][i], bh, acc[i][j], 0, 0, 0);
      }
    }
  }

  if (om == 0) {
    // bf16 U via LDS transpose (reuse sW as ushort [128][132])
    __syncthreads();
    unsigned short* Tb = (unsigned short*)sW;
#pragma unroll
    for (int i = 0; i < 2; ++i)
#pragma unroll
      for (int j = 0; j < 4; ++j)
#pragma unroll
        for (int rg = 0; rg < 4; ++rg) {
          float v = acc[i][j][rg];
          unsigned int u = __float_as_uint(v);
          u += 0x7fffu + ((u >> 16) & 1);
          Tb[(wr * 32 + i * 16 + q4 * 4 + rg) * 132 + wc * 64 + j * 16 + fr] =
              (unsigned short)(u >> 16);
        }
    __syncthreads();
    int rr = t >> 2, q = t & 3;
    const unsigned short* src = Tb + rr * 132 + q * 32;
    uint4 o0 = *(const uint4*)src;
    uint4 o1 = *(const uint4*)(src + 8);
    uint4 o2 = *(const uint4*)(src + 16);
    uint4 o3 = *(const uint4*)(src + 24);
    char* drow = (char*)Ub + (size_t)(row0 + rr) * 256 + q * 64;
    *(uint4*)(drow) = o0;
    *(uint4*)(drow + 16) = o1;
    *(uint4*)(drow + 32) = o2;
    *(uint4*)(drow + 48) = o3;
  } else {
#pragma unroll
    for (int i = 0; i < 2; ++i)
#pragma unroll
      for (int j = 0; j < 4; ++j)
#pragma unroll
        for (int rg = 0; rg < 4; ++rg)
          V[(size_t)(row0 + wr * 32 + i * 16 + q4 * 4 + rg) * D_H + wc * 64 + j * 16 + fr] =
              acc[i][j][rg];
  }
}

// ---------------- fused aggregate + epilogue (+ optional score) ----------------
// h' = relu( mean-gather(Ub bf16) + V + bias )
// OUTP=1 -> pair out to Hp.  OUTP=0 -> fp32 in-place into V + fused attention
// score (dot with watt, wave butterfly reduce) + per-block partmax.

template <int OUTP>
__global__ __launch_bounds__(256) void k_aggfin(const unsigned short* __restrict__ Ub,
                                                float* __restrict__ V,
                                                const float* __restrict__ bias,
                                                const int* __restrict__ row_ptr,
                                                const int* __restrict__ col,
                                                unsigned short* __restrict__ Hp,
                                                const float* __restrict__ watt,
                                                const float* __restrict__ batt,
                                                float* __restrict__ scores,
                                                float* __restrict__ partmax, int N) {
  __shared__ float smax[4];
  int wv = threadIdx.x >> 6;
  int wid = blockIdx.x * 4 + wv;
  int lane = threadIdx.x & 63;
  bool valid = wid < N;
  if (OUTP == 1 && !valid) return;

  float ax = 0.f, ay = 0.f;
  float ox = 0.f, oy = 0.f;
  if (valid) {
    const unsigned int* uvb = (const unsigned int*)Ub;
    int e0 = row_ptr[wid], e1 = row_ptr[wid + 1];
    int e = e0;
    for (; e + 4 <= e1; e += 4) {
      int s0 = col[e], s1 = col[e + 1], s2 = col[e + 2], s3 = col[e + 3];
      unsigned int u0 = uvb[(size_t)s0 * 64 + lane];
      unsigned int u1 = uvb[(size_t)s1 * 64 + lane];
      unsigned int u2 = uvb[(size_t)s2 * 64 + lane];
      unsigned int u3 = uvb[(size_t)s3 * 64 + lane];
      ax += blo(u0) + blo(u1) + blo(u2) + blo(u3);
      ay += bhi(u0) + bhi(u1) + bhi(u2) + bhi(u3);
    }
    for (; e < e1; ++e) {
      unsigned int u = uvb[(size_t)col[e] * 64 + lane];
      ax += blo(u);
      ay += bhi(u);
    }
    float inv = 1.f / fmaxf((float)(e1 - e0), 1.f);
    float2 vv = ((const float2*)V)[(size_t)wid * 64 + lane];
    float2 bb = ((const float2*)bias)[lane];
    ox = fmaxf(ax * inv + vv.x + bb.x, 0.f);
    oy = fmaxf(ay * inv + vv.y + bb.y, 0.f);
    if (OUTP) {
      unsigned short hx, lx, hy, ly;
      split_bf16(ox, hx, lx);
      split_bf16(oy, hy, ly);
      ((unsigned int*)((char*)Hp + (size_t)wid * 512))[lane] =
          (unsigned int)hx | ((unsigned int)hy << 16);
      ((unsigned int*)((char*)Hp + (size_t)wid * 512 + 256))[lane] =
          (unsigned int)lx | ((unsigned int)ly << 16);
    } else {
      ((float2*)V)[(size_t)wid * 64 + lane] = make_float2(ox, oy);
    }
  }

  if (OUTP == 0) {
    // fused attention score
    float sc = -3.0e38f;
    float2 w = ((const float2*)watt)[lane];
    float p = ox * w.x + oy * w.y;
#pragma unroll
    for (int off = 1; off < 64; off <<= 1) p += __shfl_xor(p, off);
    if (valid) {
      sc = p + batt[0];
      if (lane == 0) scores[wid] = sc;
    }
    if (lane == 0) smax[wv] = sc;
    __syncthreads();
    if (threadIdx.x == 0)
      partmax[blockIdx.x] = fmaxf(fmaxf(smax[0], smax[1]), fmaxf(smax[2], smax[3]));
  }
}

// ---------------- attention readout tail ----------------

__global__ __launch_bounds__(256) void k_redmax(const float* __restrict__ partmax, int PB,
                                                float* __restrict__ red) {
  __shared__ float sm[256];
  int t = threadIdx.x;
  float m = -3.0e38f;
  for (int i = t; i < PB; i += 256) m = fmaxf(m, partmax[i]);
  sm[t] = m;
  __syncthreads();
  for (int off = 128; off > 0; off >>= 1) {
    if (t < off) sm[t] = fmaxf(sm[t], sm[t + off]);
    __syncthreads();
  }
  if (t == 0) {
    red[0] = sm[0];
    red[1] = 0.f;
  }
  for (int i = t; i < 1024; i += 256) red[2 + i] = 0.f;
}

__global__ __launch_bounds__(256) void k_pool(const float* __restrict__ h,
                                              const float* __restrict__ scores,
                                              const int* __restrict__ batch,
                                              float* __restrict__ red, int N, int nblocks) {
  __shared__ float pl[4][1024];
  __shared__ float zp[4];
  int t = threadIdx.x;
  int w = t >> 6, lane = t & 63;
  for (int i = lane; i < 1024; i += 64) pl[w][i] = 0.f;
  float M = red[0];
  float zacc = 0.f;
  const float2* hv = (const float2*)h;
  int stride = nblocks * 4;
  for (int node = blockIdx.x * 4 + w; node < N; node += stride) {
    float wgt = __expf(scores[node] - M);
    int b = batch[node];
    float2 v = hv[(size_t)node * 64 + lane];
    pl[w][b * 128 + lane * 2] += v.x * wgt;
    pl[w][b * 128 + lane * 2 + 1] += v.y * wgt;
    zacc += wgt;
  }
  if (lane == 0) zp[w] = zacc;
  __syncthreads();
  for (int i = t; i < 1024; i += 256) {
    float s = pl[0][i] + pl[1][i] + pl[2][i] + pl[3][i];
    atomicAdd(&red[2 + i], s);
  }
  if (t == 0) atomicAdd(&red[1], zp[0] + zp[1] + zp[2] + zp[3]);
}

__global__ __launch_bounds__(512) void k_out(const float* __restrict__ red,
                                             const float* __restrict__ Wout,
                                             const float* __restrict__ bout,
                                             float* __restrict__ out) {
  int t = threadIdx.x;
  int gIdx = t >> 6, o = t & 63;
  float invZ = 1.f / red[1];
  const float* p = red + 2 + gIdx * 128;
  const float* wr = Wout + (size_t)o * 128;
  float acc = 0.f;
  for (int k = 0; k < 128; ++k) acc = fmaf(p[k], wr[k], acc);
  out[gIdx * 64 + o] = acc * invZ + bout[o];
}

// ---------------- launcher ----------------

extern "C" void kernel_launch(void* const* d_in, const int* in_sizes, int n_in,
                              void* d_out, int out_size, void* d_ws, size_t ws_size,
                              hipStream_t stream) {
  const float* x     = (const float*)d_in[0];
  const int*   ei    = (const int*)d_in[1];
  const int*   batch = (const int*)d_in[2];
  const float* W_emb = (const float*)d_in[3];
  const float* b_emb = (const float*)d_in[4];
  const float* Wl0   = (const float*)d_in[5];
  const float* bl0   = (const float*)d_in[6];
  const float* Wr0   = (const float*)d_in[7];
  const float* Wl1   = (const float*)d_in[8];
  const float* bl1   = (const float*)d_in[9];
  const float* Wr1   = (const float*)d_in[10];
  const float* W_att = (const float*)d_in[11];
  const float* b_att = (const float*)d_in[12];
  const float* W_out = (const float*)d_in[13];
  const float* b_out = (const float*)d_in[14];
  float* out = (float*)d_out;

  const int DIN = 300;
  int N = in_sizes[0] / DIN;
  int E = in_sizes[1] / 2;
  int Npad = (N + 127) & ~127;

  char* wsp = (char*)d_ws;
  size_t off = 0;
  auto carve = [&](size_t bytes) -> void* {
    void* p = wsp + off;
    off += (bytes + 255) & ~(size_t)255;
    return p;
  };
  unsigned short* P  = (unsigned short*)carve((size_t)Npad * 512);  // h pairs
  unsigned short* Ub = (unsigned short*)carve((size_t)Npad * 256);  // A@Wl bf16
  float*          V  = (float*)carve((size_t)Npad * 512);           // A@Wr fp32 / h2
  unsigned short* WembP = (unsigned short*)carve((size_t)128 * 640 * 2);
  unsigned short* WP0l  = (unsigned short*)carve((size_t)128 * 256 * 2);
  unsigned short* WP0r  = (unsigned short*)carve((size_t)128 * 256 * 2);
  unsigned short* WP1l  = (unsigned short*)carve((size_t)128 * 256 * 2);
  unsigned short* WP1r  = (unsigned short*)carve((size_t)128 * 256 * 2);
  int*   colA    = (int*)carve((size_t)E * 4);
  int*   row_ptr = (int*)carve((size_t)(N + 1) * 4);
  int*   deg     = (int*)carve((size_t)N * 4);
  int*   cnt     = (int*)carve((size_t)N * 4);
  float* scores  = (float*)carve((size_t)N * 4);
  int aggBlocks = (N + 3) / 4;
  float* partmax = (float*)carve((size_t)aggBlocks * 4);
  float* red     = (float*)carve((size_t)(2 + 1024) * 4);
  int scanBlocks = (N + 255) / 256;
  int*   partials = (int*)carve((size_t)scanBlocks * 4);

  const int* srcv = ei;
  const int* dstv = ei + E;

  hipMemsetAsync(deg, 0, (size_t)N * 4, stream);
  k_deg<<<1024, 256, 0, stream>>>(dstv, deg, E);
  k_wsplit<<<(128 * 320 + 4 * 16384 + 255) / 256, 256, 0, stream>>>(
      W_emb, Wl0, Wr0, Wl1, Wr1, WembP, WP0l, WP0r, WP1l, WP1r);
  k_partial<<<scanBlocks, 256, 0, stream>>>(deg, partials, N);
  k_scanpart<<<1, 256, 0, stream>>>(partials, scanBlocks, row_ptr, N);
  k_rowptr<<<scanBlocks, 256, 0, stream>>>(deg, partials, row_ptr, cnt, N);
  k_scatter<<<1024, 256, 0, stream>>>(srcv, dstv, cnt, colA, E);

  dim3 gemb(Npad / 128, 2);
  k_emb<<<gemb, 512, 0, stream>>>(x, WembP, b_emb, P, N);

  dim3 gconv(Npad / 128, 2);
  // conv0 + aggfin -> pair P
  k_conv<<<gconv, 512, 0, stream>>>(P, WP0l, WP0r, Ub, V);
  k_aggfin<1><<<aggBlocks, 256, 0, stream>>>(Ub, V, bl0, row_ptr, colA, P,
                                             nullptr, nullptr, nullptr, nullptr, N);
  // conv1 + aggfin (fp32 in-place into V) + fused score
  k_conv<<<gconv, 512, 0, stream>>>(P, WP1l, WP1r, Ub, V);
  k_aggfin<0><<<aggBlocks, 256, 0, stream>>>(Ub, V, bl1, row_ptr, colA, nullptr,
                                             W_att, b_att, scores, partmax, N);

  const float* h2 = (const float*)V;
  k_redmax<<<1, 256, 0, stream>>>(partmax, aggBlocks, red);
  k_pool<<<256, 256, 0, stream>>>(h2, scores, batch, red, N, 256);
  k_out<<<1, 512, 0, stream>>>(red, W_out, b_out, out);
}

// Round 9
// 260.055 us; speedup vs baseline: 1.6269x; 1.2350x over previous
//
#include <hip/hip_runtime.h>
#include <math.h>

#define D_H 128

typedef __attribute__((ext_vector_type(8))) __bf16 bf16x8;
typedef __attribute__((ext_vector_type(4))) float f32x4;

__device__ __forceinline__ void split_bf16(float v, unsigned short& hi, unsigned short& lo) {
  unsigned int u = __float_as_uint(v);
  hi = (unsigned short)(u >> 16);
  float l = v - __uint_as_float(u & 0xffff0000u);
  lo = (unsigned short)(__float_as_uint(l) >> 16);
}

__device__ __forceinline__ float blo(unsigned int u) { return __uint_as_float(u << 16); }
__device__ __forceinline__ float bhi(unsigned int u) { return __uint_as_float(u & 0xffff0000u); }

// pack 8 floats -> hi bf16x8 + lo bf16x8 (truncation split)
__device__ __forceinline__ void pack_pair8(const float* xv, bf16x8& ah, bf16x8& al) {
  union { bf16x8 v; unsigned int u[4]; } H, L;
#pragma unroll
  for (int e = 0; e < 4; ++e) {
    unsigned int u0 = __float_as_uint(xv[2 * e]);
    unsigned int u1 = __float_as_uint(xv[2 * e + 1]);
    float l0 = xv[2 * e] - __uint_as_float(u0 & 0xffff0000u);
    float l1 = xv[2 * e + 1] - __uint_as_float(u1 & 0xffff0000u);
    H.u[e] = (u0 >> 16) | (u1 & 0xffff0000u);
    L.u[e] = (__float_as_uint(l0) >> 16) | (__float_as_uint(l1) & 0xffff0000u);
  }
  ah = H.v;
  al = L.v;
}

__device__ __forceinline__ void load_lds16(const void* g, void* l) {
  __builtin_amdgcn_global_load_lds((const __attribute__((address_space(1))) unsigned int*)g,
                                   (__attribute__((address_space(3))) unsigned int*)l,
                                   16, 0, 0);
}

// ---------------- graph build: bucketed two-level CSR ----------------
// bucket b = dst >> 8 (256 nodes per bucket). Packed edge: src (16b) | dstLocal<<16.

__global__ __launch_bounds__(256) void k_hist(const int* __restrict__ dstv,
                                              int* __restrict__ bucketCnt, int E) {
  __shared__ int h[256];
  int t = threadIdx.x;
  h[t] = 0;
  __syncthreads();
  for (int i = blockIdx.x * 256 + t; i < E; i += gridDim.x * 256)
    atomicAdd(&h[dstv[i] >> 8], 1);
  __syncthreads();
  if (h[t]) atomicAdd(&bucketCnt[t], h[t]);
}

__global__ __launch_bounds__(256) void k_bucketscan(const int* __restrict__ bucketCnt, int NB,
                                                    int* __restrict__ bucketBase,
                                                    int* __restrict__ cursor,
                                                    int* __restrict__ row_ptr, int N, int E) {
  __shared__ int s[256];
  int t = threadIdx.x;
  int v = (t < NB) ? bucketCnt[t] : 0;
  s[t] = v;
  __syncthreads();
  for (int off = 1; off < 256; off <<= 1) {
    int u = (t >= off) ? s[t - off] : 0;
    __syncthreads();
    s[t] += u;
    __syncthreads();
  }
  int excl = s[t] - v;
  if (t < NB) {
    bucketBase[t] = excl;
    cursor[t] = excl;
  }
  if (t == NB - 1) bucketBase[NB] = excl + v;
  if (t == 0) row_ptr[N] = E;
}

__global__ __launch_bounds__(256) void k_binscatter(const int* __restrict__ srcv,
                                                    const int* __restrict__ dstv,
                                                    int* __restrict__ cursor,
                                                    unsigned int* __restrict__ tmp, int E) {
  __shared__ int h[256];
  __shared__ int base[256];
  int t = threadIdx.x;
  int chunk = (E + gridDim.x - 1) / gridDim.x;
  int c0 = blockIdx.x * chunk;
  int c1 = min(c0 + chunk, E);
  int dst[16], src[16];
  h[t] = 0;
  __syncthreads();
#pragma unroll
  for (int p = 0; p < 16; ++p) {
    int i = c0 + p * 256 + t;
    if (i < c1) {
      dst[p] = dstv[i];
      src[p] = srcv[i];
      atomicAdd(&h[dst[p] >> 8], 1);
    } else {
      dst[p] = -1;
      src[p] = 0;
    }
  }
  __syncthreads();
  int cnt = h[t];
  __syncthreads();
  base[t] = cnt ? atomicAdd(&cursor[t], cnt) : 0;
  h[t] = 0;
  __syncthreads();
#pragma unroll
  for (int p = 0; p < 16; ++p) {
    if (dst[p] >= 0) {
      int b = dst[p] >> 8;
      int pos = base[b] + atomicAdd(&h[b], 1);
      tmp[pos] = (unsigned int)src[p] | ((unsigned int)(dst[p] & 255) << 16);
    }
  }
}

__global__ __launch_bounds__(256) void k_localcsr(const unsigned int* __restrict__ tmp,
                                                  const int* __restrict__ bucketBase,
                                                  int* __restrict__ row_ptr,
                                                  int* __restrict__ col, int N) {
  __shared__ int deg[256], rp[256], cur[256];
  int b = blockIdx.x, t = threadIdx.x;
  int s = bucketBase[b], e = bucketBase[b + 1];
  int epb = e - s;
  deg[t] = 0;
  __syncthreads();
  for (int i = t; i < epb; i += 256) atomicAdd(&deg[tmp[s + i] >> 16], 1);
  __syncthreads();
  int v = deg[t];
  rp[t] = v;
  __syncthreads();
  for (int off = 1; off < 256; off <<= 1) {
    int u = (t >= off) ? rp[t - off] : 0;
    __syncthreads();
    rp[t] += u;
    __syncthreads();
  }
  int excl = rp[t] - v;
  rp[t] = excl;
  cur[t] = 0;
  int gid = b * 256 + t;
  if (gid < N) row_ptr[gid] = s + excl;
  __syncthreads();
  for (int i = t; i < epb; i += 256) {
    unsigned int p = tmp[s + i];
    int dl = p >> 16;
    int pos = s + rp[dl] + atomicAdd(&cur[dl], 1);
    col[pos] = (int)(p & 0xffffu);
  }
}

// ---------------- weight split + SWIZZLE (once) ----------------

__global__ __launch_bounds__(256) void k_wsplit(
    const float* __restrict__ Wemb, const float* __restrict__ Wl0,
    const float* __restrict__ Wr0, const float* __restrict__ Wl1,
    const float* __restrict__ Wr1, unsigned short* __restrict__ WembP,
    unsigned short* __restrict__ P0l, unsigned short* __restrict__ P0r,
    unsigned short* __restrict__ P1l, unsigned short* __restrict__ P1r) {
  int tid = blockIdx.x * 256 + threadIdx.x;
  const int EMB = 128 * 320;
  if (tid < EMB) {
    int o = tid / 320, k = tid - o * 320;
    float v = (k < 300) ? Wemb[o * 300 + k] : 0.f;
    unsigned short h, l;
    split_bf16(v, h, l);
    int sw = ((2 * k) ^ ((o & 7) << 4)) >> 1;
    WembP[o * 640 + sw] = h;
    WembP[o * 640 + 320 + sw] = l;
  } else if (tid < EMB + 4 * 16384) {
    int r = tid - EMB;
    int m = r >> 14;
    int i = r & 16383;
    int o = i >> 7, k = i & 127;
    const float* W = (m == 0) ? Wl0 : (m == 1) ? Wr0 : (m == 2) ? Wl1 : Wr1;
    unsigned short* P = (m == 0) ? P0l : (m == 1) ? P0r : (m == 2) ? P1l : P1r;
    unsigned short h, l;
    split_bf16(W[o * 128 + k], h, l);
    int sw = ((2 * k) ^ ((o & 7) << 4)) >> 1;
    P[o * 256 + sw] = h;
    P[o * 256 + 128 + sw] = l;
  }
}

// ---------------- emb GEMM: P = pair( x @ Wemb^T + b ) ----------------

__global__ __launch_bounds__(512, 4) void k_emb(const float* __restrict__ x,
                                                const unsigned short* __restrict__ Wp,
                                                const float* __restrict__ bias,
                                                unsigned short* __restrict__ P, int N) {
  __shared__ alignas(16) char sW[49152];
  int t = threadIdx.x, lane = t & 63, wave = t >> 6;
  int ch = blockIdx.y;
  int row0 = blockIdx.x * 128;
  int fr = lane & 15, q4 = lane >> 4;
  int X = (fr & 7) << 4;
  int row = row0 + wave * 16 + fr;
  if (row >= N) row = N - 1;
  const float* xrp = x + (size_t)row * 300;
  const char* Wbase = (const char*)Wp + (size_t)ch * 64 * 1280;
  f32x4 acc[4] = {};
  float xb[2][8];

  auto stage = [&](int CB, int HS, int kb, int nround) {
    for (int r = 0; r < nround; ++r) {
      int off = r * 8192 + wave * 1024;
      int offl = off + lane * 16;
      int c = offl / CB;
      int w = offl - c * CB;
      const char* src = Wbase + (size_t)c * 1280 + (w < HS ? kb + w : 640 + kb + (w - HS));
      load_lds16(src, sW + off);
    }
  };
  auto loadx = [&](float* d, int c0) {
    if (c0 + 7 < 300) {
      float4 a = *(const float4*)(xrp + c0);
      float4 b = *(const float4*)(xrp + c0 + 4);
      d[0] = a.x; d[1] = a.y; d[2] = a.z; d[3] = a.w;
      d[4] = b.x; d[5] = b.y; d[6] = b.z; d[7] = b.w;
    } else {
#pragma unroll
      for (int e = 0; e < 8; ++e) d[e] = (c0 + e < 300) ? xrp[c0 + e] : 0.f;
    }
  };

  stage(768, 384, 0, 6);
  loadx(xb[0], q4 * 8);
  __syncthreads();

#pragma unroll
  for (int ks = 0; ks < 6; ++ks) {
    loadx(xb[(ks + 1) & 1], (ks + 1) * 32 + q4 * 8);
    bf16x8 bh[4], bl[4];
#pragma unroll
    for (int j = 0; j < 4; ++j) {
      int c64 = j * 16 + fr;
      int ko = (ks * 64 + q4 * 16) ^ X;
      bh[j] = *(const bf16x8*)(sW + c64 * 768 + ko);
      bl[j] = *(const bf16x8*)(sW + c64 * 768 + 384 + ko);
    }
    bf16x8 ah, al;
    pack_pair8(xb[ks & 1], ah, al);
#pragma unroll
    for (int j = 0; j < 4; ++j) {
      acc[j] = __builtin_amdgcn_mfma_f32_16x16x32_bf16(ah, bh[j], acc[j], 0, 0, 0);
      acc[j] = __builtin_amdgcn_mfma_f32_16x16x32_bf16(ah, bl[j], acc[j], 0, 0, 0);
      acc[j] = __builtin_amdgcn_mfma_f32_16x16x32_bf16(al, bh[j], acc[j], 0, 0, 0);
    }
  }
  __syncthreads();
  stage(512, 256, 384, 4);
  __syncthreads();

#pragma unroll
  for (int ks2 = 0; ks2 < 4; ++ks2) {
    int ks = 6 + ks2;
    if (ks < 9) loadx(xb[(ks + 1) & 1], (ks + 1) * 32 + q4 * 8);
    bf16x8 bh[4], bl[4];
#pragma unroll
    for (int j = 0; j < 4; ++j) {
      int c64 = j * 16 + fr;
      int ko = (ks2 * 64 + q4 * 16) ^ X;
      bh[j] = *(const bf16x8*)(sW + c64 * 512 + ko);
      bl[j] = *(const bf16x8*)(sW + c64 * 512 + 256 + ko);
    }
    bf16x8 ah, al;
    pack_pair8(xb[ks & 1], ah, al);
#pragma unroll
    for (int j = 0; j < 4; ++j) {
      acc[j] = __builtin_amdgcn_mfma_f32_16x16x32_bf16(ah, bh[j], acc[j], 0, 0, 0);
      acc[j] = __builtin_amdgcn_mfma_f32_16x16x32_bf16(ah, bl[j], acc[j], 0, 0, 0);
      acc[j] = __builtin_amdgcn_mfma_f32_16x16x32_bf16(al, bh[j], acc[j], 0, 0, 0);
    }
  }
  __syncthreads();

  float* T = (float*)sW;
#pragma unroll
  for (int j = 0; j < 4; ++j) {
    float b = bias[ch * 64 + j * 16 + fr];
#pragma unroll
    for (int rg = 0; rg < 4; ++rg)
      T[(wave * 16 + q4 * 4 + rg) * 66 + j * 16 + fr] = acc[j][rg] + b;
  }
  __syncthreads();
  int rr = t >> 2, q = t & 3;
  float vals[16];
#pragma unroll
  for (int c = 0; c < 16; ++c) vals[c] = T[rr * 66 + q * 16 + c];
  unsigned int hu[8], lu[8];
#pragma unroll
  for (int e = 0; e < 8; ++e) {
    unsigned int u0 = __float_as_uint(vals[2 * e]);
    unsigned int u1 = __float_as_uint(vals[2 * e + 1]);
    float l0 = vals[2 * e] - __uint_as_float(u0 & 0xffff0000u);
    float l1 = vals[2 * e + 1] - __uint_as_float(u1 & 0xffff0000u);
    hu[e] = (u0 >> 16) | (u1 & 0xffff0000u);
    lu[e] = (__float_as_uint(l0) >> 16) | (__float_as_uint(l1) & 0xffff0000u);
  }
  char* rowp = (char*)P + (size_t)(row0 + rr) * 512 + ch * 128;
  *(uint4*)(rowp + q * 32) = make_uint4(hu[0], hu[1], hu[2], hu[3]);
  *(uint4*)(rowp + q * 32 + 16) = make_uint4(hu[4], hu[5], hu[6], hu[7]);
  *(uint4*)(rowp + 256 + q * 32) = make_uint4(lu[0], lu[1], lu[2], lu[3]);
  *(uint4*)(rowp + 256 + q * 32 + 16) = make_uint4(lu[4], lu[5], lu[6], lu[7]);
}

// ---------------- conv GEMM ----------------
// blockIdx.y==0: U = A@Wl^T as PACKED BF16 [row][128 ushort] via LDS transpose.
// blockIdx.y==1: V = A@Wr^T as fp32 direct stores.

__global__ __launch_bounds__(512, 4) void k_conv(const unsigned short* __restrict__ Ap,
                                                 const unsigned short* __restrict__ Wl,
                                                 const unsigned short* __restrict__ Wr,
                                                 unsigned short* __restrict__ Ub,
                                                 float* __restrict__ V) {
  __shared__ alignas(16) char sW[65536];
  int t = threadIdx.x, lane = t & 63, wave = t >> 6;
  int wr = wave >> 1, wc = wave & 1;
  int om = blockIdx.y;
  const char* Wg = (const char*)(om ? Wr : Wl);
  int row0 = blockIdx.x * 128;
  int fr = lane & 15, q4 = lane >> 4;
  int X = (fr & 7) << 4;

  for (int r = 0; r < 8; ++r) {
    int off = r * 8192 + wave * 1024;
    load_lds16(Wg + off + lane * 16, sW + off);
  }

  const char* a0 = (const char*)Ap + (size_t)(row0 + wr * 32 + fr) * 512 + q4 * 16;
  const char* a1 = a0 + 16 * 512;
  bf16x8 ah[2][2], al[2][2];
  ah[0][0] = *(const bf16x8*)a0;
  al[0][0] = *(const bf16x8*)(a0 + 256);
  ah[0][1] = *(const bf16x8*)a1;
  al[0][1] = *(const bf16x8*)(a1 + 256);

  f32x4 acc[2][4] = {};
  __syncthreads();

#pragma unroll
  for (int ks = 0; ks < 4; ++ks) {
    if (ks < 3) {
      int nb = (ks + 1) * 64;
      ah[(ks + 1) & 1][0] = *(const bf16x8*)(a0 + nb);
      al[(ks + 1) & 1][0] = *(const bf16x8*)(a0 + nb + 256);
      ah[(ks + 1) & 1][1] = *(const bf16x8*)(a1 + nb);
      al[(ks + 1) & 1][1] = *(const bf16x8*)(a1 + nb + 256);
    }
#pragma unroll
    for (int j = 0; j < 4; ++j) {
      int c = wc * 64 + j * 16 + fr;
      int ko = (ks * 64 + q4 * 16) ^ X;
      bf16x8 bh = *(const bf16x8*)(sW + c * 512 + ko);
      bf16x8 bl = *(const bf16x8*)(sW + c * 512 + 256 + ko);
#pragma unroll
      for (int i = 0; i < 2; ++i) {
        acc[i][j] = __builtin_amdgcn_mfma_f32_16x16x32_bf16(ah[ks & 1][i], bh, acc[i][j], 0, 0, 0);
        acc[i][j] = __builtin_amdgcn_mfma_f32_16x16x32_bf16(ah[ks & 1][i], bl, acc[i][j], 0, 0, 0);
        acc[i][j] = __builtin_amdgcn_mfma_f32_16x16x32_bf16(al[ks & 1][i], bh, acc[i][j], 0, 0, 0);
      }
    }
  }

  if (om == 0) {
    __syncthreads();
    unsigned short* Tb = (unsigned short*)sW;
#pragma unroll
    for (int i = 0; i < 2; ++i)
#pragma unroll
      for (int j = 0; j < 4; ++j)
#pragma unroll
        for (int rg = 0; rg < 4; ++rg) {
          float v = acc[i][j][rg];
          unsigned int u = __float_as_uint(v);
          u += 0x7fffu + ((u >> 16) & 1);
          Tb[(wr * 32 + i * 16 + q4 * 4 + rg) * 132 + wc * 64 + j * 16 + fr] =
              (unsigned short)(u >> 16);
        }
    __syncthreads();
    int rr = t >> 2, q = t & 3;
    const unsigned short* src = Tb + rr * 132 + q * 32;
    uint4 o0 = *(const uint4*)src;
    uint4 o1 = *(const uint4*)(src + 8);
    uint4 o2 = *(const uint4*)(src + 16);
    uint4 o3 = *(const uint4*)(src + 24);
    char* drow = (char*)Ub + (size_t)(row0 + rr) * 256 + q * 64;
    *(uint4*)(drow) = o0;
    *(uint4*)(drow + 16) = o1;
    *(uint4*)(drow + 32) = o2;
    *(uint4*)(drow + 48) = o3;
  } else {
#pragma unroll
    for (int i = 0; i < 2; ++i)
#pragma unroll
      for (int j = 0; j < 4; ++j)
#pragma unroll
        for (int rg = 0; rg < 4; ++rg)
          V[(size_t)(row0 + wr * 32 + i * 16 + q4 * 4 + rg) * D_H + wc * 64 + j * 16 + fr] =
              acc[i][j][rg];
  }
}

// ---------------- fused aggregate + epilogue (+ optional score) ----------------

template <int OUTP>
__global__ __launch_bounds__(256) void k_aggfin(const unsigned short* __restrict__ Ub,
                                                float* __restrict__ V,
                                                const float* __restrict__ bias,
                                                const int* __restrict__ row_ptr,
                                                const int* __restrict__ col,
                                                unsigned short* __restrict__ Hp,
                                                const float* __restrict__ watt,
                                                const float* __restrict__ batt,
                                                float* __restrict__ scores,
                                                float* __restrict__ partmax, int N) {
  __shared__ float smax[4];
  int wv = threadIdx.x >> 6;
  int wid = blockIdx.x * 4 + wv;
  int lane = threadIdx.x & 63;
  bool valid = wid < N;
  if (OUTP == 1 && !valid) return;

  float ax = 0.f, ay = 0.f;
  float ox = 0.f, oy = 0.f;
  if (valid) {
    const unsigned int* uvb = (const unsigned int*)Ub;
    int e0 = row_ptr[wid], e1 = row_ptr[wid + 1];
    int e = e0;
    for (; e + 4 <= e1; e += 4) {
      int s0 = col[e], s1 = col[e + 1], s2 = col[e + 2], s3 = col[e + 3];
      unsigned int u0 = uvb[(size_t)s0 * 64 + lane];
      unsigned int u1 = uvb[(size_t)s1 * 64 + lane];
      unsigned int u2 = uvb[(size_t)s2 * 64 + lane];
      unsigned int u3 = uvb[(size_t)s3 * 64 + lane];
      ax += blo(u0) + blo(u1) + blo(u2) + blo(u3);
      ay += bhi(u0) + bhi(u1) + bhi(u2) + bhi(u3);
    }
    for (; e < e1; ++e) {
      unsigned int u = uvb[(size_t)col[e] * 64 + lane];
      ax += blo(u);
      ay += bhi(u);
    }
    float inv = 1.f / fmaxf((float)(e1 - e0), 1.f);
    float2 vv = ((const float2*)V)[(size_t)wid * 64 + lane];
    float2 bb = ((const float2*)bias)[lane];
    ox = fmaxf(ax * inv + vv.x + bb.x, 0.f);
    oy = fmaxf(ay * inv + vv.y + bb.y, 0.f);
    if (OUTP) {
      unsigned short hx, lx, hy, ly;
      split_bf16(ox, hx, lx);
      split_bf16(oy, hy, ly);
      ((unsigned int*)((char*)Hp + (size_t)wid * 512))[lane] =
          (unsigned int)hx | ((unsigned int)hy << 16);
      ((unsigned int*)((char*)Hp + (size_t)wid * 512 + 256))[lane] =
          (unsigned int)lx | ((unsigned int)ly << 16);
    } else {
      ((float2*)V)[(size_t)wid * 64 + lane] = make_float2(ox, oy);
    }
  }

  if (OUTP == 0) {
    float sc = -3.0e38f;
    float2 w = ((const float2*)watt)[lane];
    float p = ox * w.x + oy * w.y;
#pragma unroll
    for (int off = 1; off < 64; off <<= 1) p += __shfl_xor(p, off);
    if (valid) {
      sc = p + batt[0];
      if (lane == 0) scores[wid] = sc;
    }
    if (lane == 0) smax[wv] = sc;
    __syncthreads();
    if (threadIdx.x == 0)
      partmax[blockIdx.x] = fmaxf(fmaxf(smax[0], smax[1]), fmaxf(smax[2], smax[3]));
  }
}

// ---------------- attention readout tail ----------------

__global__ __launch_bounds__(256) void k_redmax(const float* __restrict__ partmax, int PB,
                                                float* __restrict__ red) {
  __shared__ float sm[256];
  int t = threadIdx.x;
  float m = -3.0e38f;
  for (int i = t; i < PB; i += 256) m = fmaxf(m, partmax[i]);
  sm[t] = m;
  __syncthreads();
  for (int off = 128; off > 0; off >>= 1) {
    if (t < off) sm[t] = fmaxf(sm[t], sm[t + off]);
    __syncthreads();
  }
  if (t == 0) {
    red[0] = sm[0];
    red[1] = 0.f;
  }
  for (int i = t; i < 1024; i += 256) red[2 + i] = 0.f;
}

__global__ __launch_bounds__(256) void k_pool(const float* __restrict__ h,
                                              const float* __restrict__ scores,
                                              const int* __restrict__ batch,
                                              float* __restrict__ red, int N, int nblocks) {
  __shared__ float pl[4][1024];
  __shared__ float zp[4];
  int t = threadIdx.x;
  int w = t >> 6, lane = t & 63;
  for (int i = lane; i < 1024; i += 64) pl[w][i] = 0.f;
  float M = red[0];
  float zacc = 0.f;
  const float2* hv = (const float2*)h;
  int stride = nblocks * 4;
  for (int node = blockIdx.x * 4 + w; node < N; node += stride) {
    float wgt = __expf(scores[node] - M);
    int b = batch[node];
    float2 v = hv[(size_t)node * 64 + lane];
    pl[w][b * 128 + lane * 2] += v.x * wgt;
    pl[w][b * 128 + lane * 2 + 1] += v.y * wgt;
    zacc += wgt;
  }
  if (lane == 0) zp[w] = zacc;
  __syncthreads();
  for (int i = t; i < 1024; i += 256) {
    float s = pl[0][i] + pl[1][i] + pl[2][i] + pl[3][i];
    atomicAdd(&red[2 + i], s);
  }
  if (t == 0) atomicAdd(&red[1], zp[0] + zp[1] + zp[2] + zp[3]);
}

__global__ __launch_bounds__(512) void k_out(const float* __restrict__ red,
                                             const float* __restrict__ Wout,
                                             const float* __restrict__ bout,
                                             float* __restrict__ out) {
  int t = threadIdx.x;
  int gIdx = t >> 6, o = t & 63;
  float invZ = 1.f / red[1];
  const float* p = red + 2 + gIdx * 128;
  const float* wr = Wout + (size_t)o * 128;
  float acc = 0.f;
  for (int k = 0; k < 128; ++k) acc = fmaf(p[k], wr[k], acc);
  out[gIdx * 64 + o] = acc * invZ + bout[o];
}

// ---------------- launcher ----------------

extern "C" void kernel_launch(void* const* d_in, const int* in_sizes, int n_in,
                              void* d_out, int out_size, void* d_ws, size_t ws_size,
                              hipStream_t stream) {
  const float* x     = (const float*)d_in[0];
  const int*   ei    = (const int*)d_in[1];
  const int*   batch = (const int*)d_in[2];
  const float* W_emb = (const float*)d_in[3];
  const float* b_emb = (const float*)d_in[4];
  const float* Wl0   = (const float*)d_in[5];
  const float* bl0   = (const float*)d_in[6];
  const float* Wr0   = (const float*)d_in[7];
  const float* Wl1   = (const float*)d_in[8];
  const float* bl1   = (const float*)d_in[9];
  const float* Wr1   = (const float*)d_in[10];
  const float* W_att = (const float*)d_in[11];
  const float* b_att = (const float*)d_in[12];
  const float* W_out = (const float*)d_in[13];
  const float* b_out = (const float*)d_in[14];
  float* out = (float*)d_out;

  const int DIN = 300;
  int N = in_sizes[0] / DIN;
  int E = in_sizes[1] / 2;
  int Npad = (N + 127) & ~127;
  int NB = (N + 255) / 256;

  char* wsp = (char*)d_ws;
  size_t off = 0;
  auto carve = [&](size_t bytes) -> void* {
    void* p = wsp + off;
    off += (bytes + 255) & ~(size_t)255;
    return p;
  };
  unsigned short* P  = (unsigned short*)carve((size_t)Npad * 512);  // h pairs
  unsigned short* Ub = (unsigned short*)carve((size_t)Npad * 256);  // A@Wl bf16
  float*          V  = (float*)carve((size_t)Npad * 512);           // A@Wr fp32 / h2
  unsigned short* WembP = (unsigned short*)carve((size_t)128 * 640 * 2);
  unsigned short* WP0l  = (unsigned short*)carve((size_t)128 * 256 * 2);
  unsigned short* WP0r  = (unsigned short*)carve((size_t)128 * 256 * 2);
  unsigned short* WP1l  = (unsigned short*)carve((size_t)128 * 256 * 2);
  unsigned short* WP1r  = (unsigned short*)carve((size_t)128 * 256 * 2);
  int*   colA    = (int*)carve((size_t)E * 4);
  unsigned int* tmpE = (unsigned int*)carve((size_t)E * 4);
  int*   row_ptr = (int*)carve((size_t)(N + 1) * 4);
  int*   bucketCnt  = (int*)carve((size_t)(NB + 1) * 4);
  int*   bucketBase = (int*)carve((size_t)(NB + 1) * 4);
  int*   cursor     = (int*)carve((size_t)(NB + 1) * 4);
  float* scores  = (float*)carve((size_t)N * 4);
  int aggBlocks = (N + 3) / 4;
  float* partmax = (float*)carve((size_t)aggBlocks * 4);
  float* red     = (float*)carve((size_t)(2 + 1024) * 4);

  const int* srcv = ei;
  const int* dstv = ei + E;

  hipMemsetAsync(bucketCnt, 0, (size_t)NB * 4, stream);
  k_hist<<<512, 256, 0, stream>>>(dstv, bucketCnt, E);
  k_bucketscan<<<1, 256, 0, stream>>>(bucketCnt, NB, bucketBase, cursor, row_ptr, N, E);
  k_binscatter<<<256, 256, 0, stream>>>(srcv, dstv, cursor, tmpE, E);
  k_localcsr<<<NB, 256, 0, stream>>>(tmpE, bucketBase, row_ptr, colA, N);
  k_wsplit<<<(128 * 320 + 4 * 16384 + 255) / 256, 256, 0, stream>>>(
      W_emb, Wl0, Wr0, Wl1, Wr1, WembP, WP0l, WP0r, WP1l, WP1r);

  dim3 gemb(Npad / 128, 2);
  k_emb<<<gemb, 512, 0, stream>>>(x, WembP, b_emb, P, N);

  dim3 gconv(Npad / 128, 2);
  // conv0 + aggfin -> pair P
  k_conv<<<gconv, 512, 0, stream>>>(P, WP0l, WP0r, Ub, V);
  k_aggfin<1><<<aggBlocks, 256, 0, stream>>>(Ub, V, bl0, row_ptr, colA, P,
                                             nullptr, nullptr, nullptr, nullptr, N);
  // conv1 + aggfin (fp32 in-place into V) + fused score
  k_conv<<<gconv, 512, 0, stream>>>(P, WP1l, WP1r, Ub, V);
  k_aggfin<0><<<aggBlocks, 256, 0, stream>>>(Ub, V, bl1, row_ptr, colA, nullptr,
                                             W_att, b_att, scores, partmax, N);

  const float* h2 = (const float*)V;
  k_redmax<<<1, 256, 0, stream>>>(partmax, aggBlocks, red);
  k_pool<<<256, 256, 0, stream>>>(h2, scores, batch, red, N, 256);
  k_out<<<1, 512, 0, stream>>>(red, W_out, b_out, out);
}

// Round 10
// 251.896 us; speedup vs baseline: 1.6796x; 1.0324x over previous
//
#include <hip/hip_runtime.h>
#include <math.h>

#define D_H 128

typedef __attribute__((ext_vector_type(8))) __bf16 bf16x8;
typedef __attribute__((ext_vector_type(4))) float f32x4;

__device__ __forceinline__ void split_bf16(float v, unsigned short& hi, unsigned short& lo) {
  unsigned int u = __float_as_uint(v);
  hi = (unsigned short)(u >> 16);
  float l = v - __uint_as_float(u & 0xffff0000u);
  lo = (unsigned short)(__float_as_uint(l) >> 16);
}

__device__ __forceinline__ float blo(unsigned int u) { return __uint_as_float(u << 16); }
__device__ __forceinline__ float bhi(unsigned int u) { return __uint_as_float(u & 0xffff0000u); }

// pack 8 floats -> hi bf16x8 + lo bf16x8 (truncation split)
__device__ __forceinline__ void pack_pair8(const float* xv, bf16x8& ah, bf16x8& al) {
  union { bf16x8 v; unsigned int u[4]; } H, L;
#pragma unroll
  for (int e = 0; e < 4; ++e) {
    unsigned int u0 = __float_as_uint(xv[2 * e]);
    unsigned int u1 = __float_as_uint(xv[2 * e + 1]);
    float l0 = xv[2 * e] - __uint_as_float(u0 & 0xffff0000u);
    float l1 = xv[2 * e + 1] - __uint_as_float(u1 & 0xffff0000u);
    H.u[e] = (u0 >> 16) | (u1 & 0xffff0000u);
    L.u[e] = (__float_as_uint(l0) >> 16) | (__float_as_uint(l1) & 0xffff0000u);
  }
  ah = H.v;
  al = L.v;
}

__device__ __forceinline__ void load_lds16(const void* g, void* l) {
  __builtin_amdgcn_global_load_lds((const __attribute__((address_space(1))) unsigned int*)g,
                                   (__attribute__((address_space(3))) unsigned int*)l,
                                   16, 0, 0);
}

// ---------------- graph build: bucketed two-level CSR ----------------

__global__ __launch_bounds__(256) void k_hist(const int* __restrict__ dstv,
                                              int* __restrict__ bucketCnt, int E) {
  __shared__ int h[256];
  int t = threadIdx.x;
  h[t] = 0;
  __syncthreads();
  for (int i = blockIdx.x * 256 + t; i < E; i += gridDim.x * 256)
    atomicAdd(&h[dstv[i] >> 8], 1);
  __syncthreads();
  if (h[t]) atomicAdd(&bucketCnt[t], h[t]);
}

__global__ __launch_bounds__(256) void k_bucketscan(const int* __restrict__ bucketCnt, int NB,
                                                    int* __restrict__ bucketBase,
                                                    int* __restrict__ cursor,
                                                    int* __restrict__ row_ptr, int N, int E) {
  __shared__ int s[256];
  int t = threadIdx.x;
  int v = (t < NB) ? bucketCnt[t] : 0;
  s[t] = v;
  __syncthreads();
  for (int off = 1; off < 256; off <<= 1) {
    int u = (t >= off) ? s[t - off] : 0;
    __syncthreads();
    s[t] += u;
    __syncthreads();
  }
  int excl = s[t] - v;
  if (t < NB) {
    bucketBase[t] = excl;
    cursor[t] = excl;
  }
  if (t == NB - 1) bucketBase[NB] = excl + v;
  if (t == 0) row_ptr[N] = E;
}

__global__ __launch_bounds__(256) void k_binscatter(const int* __restrict__ srcv,
                                                    const int* __restrict__ dstv,
                                                    int* __restrict__ cursor,
                                                    unsigned int* __restrict__ tmp, int E) {
  __shared__ int h[256];
  __shared__ int base[256];
  int t = threadIdx.x;
  int chunk = (E + gridDim.x - 1) / gridDim.x;
  int c0 = blockIdx.x * chunk;
  int c1 = min(c0 + chunk, E);
  int dst[16], src[16];
  h[t] = 0;
  __syncthreads();
#pragma unroll
  for (int p = 0; p < 16; ++p) {
    int i = c0 + p * 256 + t;
    if (i < c1) {
      dst[p] = dstv[i];
      src[p] = srcv[i];
      atomicAdd(&h[dst[p] >> 8], 1);
    } else {
      dst[p] = -1;
      src[p] = 0;
    }
  }
  __syncthreads();
  int cnt = h[t];
  __syncthreads();
  base[t] = cnt ? atomicAdd(&cursor[t], cnt) : 0;
  h[t] = 0;
  __syncthreads();
#pragma unroll
  for (int p = 0; p < 16; ++p) {
    if (dst[p] >= 0) {
      int b = dst[p] >> 8;
      int pos = base[b] + atomicAdd(&h[b], 1);
      tmp[pos] = (unsigned int)src[p] | ((unsigned int)(dst[p] & 255) << 16);
    }
  }
}

__global__ __launch_bounds__(256) void k_localcsr(const unsigned int* __restrict__ tmp,
                                                  const int* __restrict__ bucketBase,
                                                  int* __restrict__ row_ptr,
                                                  int* __restrict__ col, int N) {
  __shared__ int deg[256], rp[256], cur[256];
  int b = blockIdx.x, t = threadIdx.x;
  int s = bucketBase[b], e = bucketBase[b + 1];
  int epb = e - s;
  deg[t] = 0;
  __syncthreads();
  for (int i = t; i < epb; i += 256) atomicAdd(&deg[tmp[s + i] >> 16], 1);
  __syncthreads();
  int v = deg[t];
  rp[t] = v;
  __syncthreads();
  for (int off = 1; off < 256; off <<= 1) {
    int u = (t >= off) ? rp[t - off] : 0;
    __syncthreads();
    rp[t] += u;
    __syncthreads();
  }
  int excl = rp[t] - v;
  rp[t] = excl;
  cur[t] = 0;
  int gid = b * 256 + t;
  if (gid < N) row_ptr[gid] = s + excl;
  __syncthreads();
  for (int i = t; i < epb; i += 256) {
    unsigned int p = tmp[s + i];
    int dl = p >> 16;
    int pos = s + rp[dl] + atomicAdd(&cur[dl], 1);
    col[pos] = (int)(p & 0xffffu);
  }
}

// ---------------- weight split + SWIZZLE (once) ----------------

__global__ __launch_bounds__(256) void k_wsplit(
    const float* __restrict__ Wemb, const float* __restrict__ Wl0,
    const float* __restrict__ Wr0, const float* __restrict__ Wl1,
    const float* __restrict__ Wr1, unsigned short* __restrict__ WembP,
    unsigned short* __restrict__ P0l, unsigned short* __restrict__ P0r,
    unsigned short* __restrict__ P1l, unsigned short* __restrict__ P1r) {
  int tid = blockIdx.x * 256 + threadIdx.x;
  const int EMB = 128 * 320;
  if (tid < EMB) {
    int o = tid / 320, k = tid - o * 320;
    float v = (k < 300) ? Wemb[o * 300 + k] : 0.f;
    unsigned short h, l;
    split_bf16(v, h, l);
    int sw = ((2 * k) ^ ((o & 7) << 4)) >> 1;
    WembP[o * 640 + sw] = h;
    WembP[o * 640 + 320 + sw] = l;
  } else if (tid < EMB + 4 * 16384) {
    int r = tid - EMB;
    int m = r >> 14;
    int i = r & 16383;
    int o = i >> 7, k = i & 127;
    const float* W = (m == 0) ? Wl0 : (m == 1) ? Wr0 : (m == 2) ? Wl1 : Wr1;
    unsigned short* P = (m == 0) ? P0l : (m == 1) ? P0r : (m == 2) ? P1l : P1r;
    unsigned short h, l;
    split_bf16(W[o * 128 + k], h, l);
    int sw = ((2 * k) ^ ((o & 7) << 4)) >> 1;
    P[o * 256 + sw] = h;
    P[o * 256 + 128 + sw] = l;
  }
}

// ---------------- emb GEMM: P = pair( x @ Wemb^T + b ) ----------------

__global__ __launch_bounds__(512, 4) void k_emb(const float* __restrict__ x,
                                                const unsigned short* __restrict__ Wp,
                                                const float* __restrict__ bias,
                                                unsigned short* __restrict__ P, int N) {
  __shared__ alignas(16) char sW[49152];
  int t = threadIdx.x, lane = t & 63, wave = t >> 6;
  int ch = blockIdx.y;
  int row0 = blockIdx.x * 128;
  int fr = lane & 15, q4 = lane >> 4;
  int X = (fr & 7) << 4;
  int row = row0 + wave * 16 + fr;
  if (row >= N) row = N - 1;
  const float* xrp = x + (size_t)row * 300;
  const char* Wbase = (const char*)Wp + (size_t)ch * 64 * 1280;
  f32x4 acc[4] = {};
  float xb[2][8];

  auto stage = [&](int CB, int HS, int kb, int nround) {
    for (int r = 0; r < nround; ++r) {
      int off = r * 8192 + wave * 1024;
      int offl = off + lane * 16;
      int c = offl / CB;
      int w = offl - c * CB;
      const char* src = Wbase + (size_t)c * 1280 + (w < HS ? kb + w : 640 + kb + (w - HS));
      load_lds16(src, sW + off);
    }
  };
  auto loadx = [&](float* d, int c0) {
    if (c0 + 7 < 300) {
      float4 a = *(const float4*)(xrp + c0);
      float4 b = *(const float4*)(xrp + c0 + 4);
      d[0] = a.x; d[1] = a.y; d[2] = a.z; d[3] = a.w;
      d[4] = b.x; d[5] = b.y; d[6] = b.z; d[7] = b.w;
    } else {
#pragma unroll
      for (int e = 0; e < 8; ++e) d[e] = (c0 + e < 300) ? xrp[c0 + e] : 0.f;
    }
  };

  stage(768, 384, 0, 6);
  loadx(xb[0], q4 * 8);
  __syncthreads();

#pragma unroll
  for (int ks = 0; ks < 6; ++ks) {
    loadx(xb[(ks + 1) & 1], (ks + 1) * 32 + q4 * 8);
    bf16x8 bh[4], bl[4];
#pragma unroll
    for (int j = 0; j < 4; ++j) {
      int c64 = j * 16 + fr;
      int ko = (ks * 64 + q4 * 16) ^ X;
      bh[j] = *(const bf16x8*)(sW + c64 * 768 + ko);
      bl[j] = *(const bf16x8*)(sW + c64 * 768 + 384 + ko);
    }
    bf16x8 ah, al;
    pack_pair8(xb[ks & 1], ah, al);
#pragma unroll
    for (int j = 0; j < 4; ++j) {
      acc[j] = __builtin_amdgcn_mfma_f32_16x16x32_bf16(ah, bh[j], acc[j], 0, 0, 0);
      acc[j] = __builtin_amdgcn_mfma_f32_16x16x32_bf16(ah, bl[j], acc[j], 0, 0, 0);
      acc[j] = __builtin_amdgcn_mfma_f32_16x16x32_bf16(al, bh[j], acc[j], 0, 0, 0);
    }
  }
  __syncthreads();
  stage(512, 256, 384, 4);
  __syncthreads();

#pragma unroll
  for (int ks2 = 0; ks2 < 4; ++ks2) {
    int ks = 6 + ks2;
    if (ks < 9) loadx(xb[(ks + 1) & 1], (ks + 1) * 32 + q4 * 8);
    bf16x8 bh[4], bl[4];
#pragma unroll
    for (int j = 0; j < 4; ++j) {
      int c64 = j * 16 + fr;
      int ko = (ks2 * 64 + q4 * 16) ^ X;
      bh[j] = *(const bf16x8*)(sW + c64 * 512 + ko);
      bl[j] = *(const bf16x8*)(sW + c64 * 512 + 256 + ko);
    }
    bf16x8 ah, al;
    pack_pair8(xb[ks & 1], ah, al);
#pragma unroll
    for (int j = 0; j < 4; ++j) {
      acc[j] = __builtin_amdgcn_mfma_f32_16x16x32_bf16(ah, bh[j], acc[j], 0, 0, 0);
      acc[j] = __builtin_amdgcn_mfma_f32_16x16x32_bf16(ah, bl[j], acc[j], 0, 0, 0);
      acc[j] = __builtin_amdgcn_mfma_f32_16x16x32_bf16(al, bh[j], acc[j], 0, 0, 0);
    }
  }
  __syncthreads();

  float* T = (float*)sW;
#pragma unroll
  for (int j = 0; j < 4; ++j) {
    float b = bias[ch * 64 + j * 16 + fr];
#pragma unroll
    for (int rg = 0; rg < 4; ++rg)
      T[(wave * 16 + q4 * 4 + rg) * 66 + j * 16 + fr] = acc[j][rg] + b;
  }
  __syncthreads();
  int rr = t >> 2, q = t & 3;
  float vals[16];
#pragma unroll
  for (int c = 0; c < 16; ++c) vals[c] = T[rr * 66 + q * 16 + c];
  unsigned int hu[8], lu[8];
#pragma unroll
  for (int e = 0; e < 8; ++e) {
    unsigned int u0 = __float_as_uint(vals[2 * e]);
    unsigned int u1 = __float_as_uint(vals[2 * e + 1]);
    float l0 = vals[2 * e] - __uint_as_float(u0 & 0xffff0000u);
    float l1 = vals[2 * e + 1] - __uint_as_float(u1 & 0xffff0000u);
    hu[e] = (u0 >> 16) | (u1 & 0xffff0000u);
    lu[e] = (__float_as_uint(l0) >> 16) | (__float_as_uint(l1) & 0xffff0000u);
  }
  char* rowp = (char*)P + (size_t)(row0 + rr) * 512 + ch * 128;
  *(uint4*)(rowp + q * 32) = make_uint4(hu[0], hu[1], hu[2], hu[3]);
  *(uint4*)(rowp + q * 32 + 16) = make_uint4(hu[4], hu[5], hu[6], hu[7]);
  *(uint4*)(rowp + 256 + q * 32) = make_uint4(lu[0], lu[1], lu[2], lu[3]);
  *(uint4*)(rowp + 256 + q * 32 + 16) = make_uint4(lu[4], lu[5], lu[6], lu[7]);
}

// ---------------- conv GEMM ----------------

__global__ __launch_bounds__(512, 4) void k_conv(const unsigned short* __restrict__ Ap,
                                                 const unsigned short* __restrict__ Wl,
                                                 const unsigned short* __restrict__ Wr,
                                                 unsigned short* __restrict__ Ub,
                                                 float* __restrict__ V) {
  __shared__ alignas(16) char sW[65536];
  int t = threadIdx.x, lane = t & 63, wave = t >> 6;
  int wr = wave >> 1, wc = wave & 1;
  int om = blockIdx.y;
  const char* Wg = (const char*)(om ? Wr : Wl);
  int row0 = blockIdx.x * 128;
  int fr = lane & 15, q4 = lane >> 4;
  int X = (fr & 7) << 4;

  for (int r = 0; r < 8; ++r) {
    int off = r * 8192 + wave * 1024;
    load_lds16(Wg + off + lane * 16, sW + off);
  }

  const char* a0 = (const char*)Ap + (size_t)(row0 + wr * 32 + fr) * 512 + q4 * 16;
  const char* a1 = a0 + 16 * 512;
  bf16x8 ah[2][2], al[2][2];
  ah[0][0] = *(const bf16x8*)a0;
  al[0][0] = *(const bf16x8*)(a0 + 256);
  ah[0][1] = *(const bf16x8*)a1;
  al[0][1] = *(const bf16x8*)(a1 + 256);

  f32x4 acc[2][4] = {};
  __syncthreads();

#pragma unroll
  for (int ks = 0; ks < 4; ++ks) {
    if (ks < 3) {
      int nb = (ks + 1) * 64;
      ah[(ks + 1) & 1][0] = *(const bf16x8*)(a0 + nb);
      al[(ks + 1) & 1][0] = *(const bf16x8*)(a0 + nb + 256);
      ah[(ks + 1) & 1][1] = *(const bf16x8*)(a1 + nb);
      al[(ks + 1) & 1][1] = *(const bf16x8*)(a1 + nb + 256);
    }
#pragma unroll
    for (int j = 0; j < 4; ++j) {
      int c = wc * 64 + j * 16 + fr;
      int ko = (ks * 64 + q4 * 16) ^ X;
      bf16x8 bh = *(const bf16x8*)(sW + c * 512 + ko);
      bf16x8 bl = *(const bf16x8*)(sW + c * 512 + 256 + ko);
#pragma unroll
      for (int i = 0; i < 2; ++i) {
        acc[i][j] = __builtin_amdgcn_mfma_f32_16x16x32_bf16(ah[ks & 1][i], bh, acc[i][j], 0, 0, 0);
        acc[i][j] = __builtin_amdgcn_mfma_f32_16x16x32_bf16(ah[ks & 1][i], bl, acc[i][j], 0, 0, 0);
        acc[i][j] = __builtin_amdgcn_mfma_f32_16x16x32_bf16(al[ks & 1][i], bh, acc[i][j], 0, 0, 0);
      }
    }
  }

  if (om == 0) {
    __syncthreads();
    unsigned short* Tb = (unsigned short*)sW;
#pragma unroll
    for (int i = 0; i < 2; ++i)
#pragma unroll
      for (int j = 0; j < 4; ++j)
#pragma unroll
        for (int rg = 0; rg < 4; ++rg) {
          float v = acc[i][j][rg];
          unsigned int u = __float_as_uint(v);
          u += 0x7fffu + ((u >> 16) & 1);
          Tb[(wr * 32 + i * 16 + q4 * 4 + rg) * 132 + wc * 64 + j * 16 + fr] =
              (unsigned short)(u >> 16);
        }
    __syncthreads();
    int rr = t >> 2, q = t & 3;
    const unsigned short* src = Tb + rr * 132 + q * 32;
    uint4 o0 = *(const uint4*)src;
    uint4 o1 = *(const uint4*)(src + 8);
    uint4 o2 = *(const uint4*)(src + 16);
    uint4 o3 = *(const uint4*)(src + 24);
    char* drow = (char*)Ub + (size_t)(row0 + rr) * 256 + q * 64;
    *(uint4*)(drow) = o0;
    *(uint4*)(drow + 16) = o1;
    *(uint4*)(drow + 32) = o2;
    *(uint4*)(drow + 48) = o3;
  } else {
#pragma unroll
    for (int i = 0; i < 2; ++i)
#pragma unroll
      for (int j = 0; j < 4; ++j)
#pragma unroll
        for (int rg = 0; rg < 4; ++rg)
          V[(size_t)(row0 + wr * 32 + i * 16 + q4 * 4 + rg) * D_H + wc * 64 + j * 16 + fr] =
              acc[i][j][rg];
  }
}

// ---------------- fused aggregate + epilogue (+ optional score) ----------------
// MLP-optimized gather: lane reads uint2 (4 bf16 dims); 32 lanes cover a row,
// two half-waves process two different edges per load -> 8 edges in flight.

template <int OUTP>
__global__ __launch_bounds__(256) void k_aggfin(const unsigned short* __restrict__ Ub,
                                                float* __restrict__ V,
                                                const float* __restrict__ bias,
                                                const int* __restrict__ row_ptr,
                                                const int* __restrict__ col,
                                                unsigned short* __restrict__ Hp,
                                                const float* __restrict__ watt,
                                                const float* __restrict__ batt,
                                                float* __restrict__ scores,
                                                float* __restrict__ partmax, int N) {
  __shared__ float smax[4];
  int wv = threadIdx.x >> 6;
  int wid = blockIdx.x * 4 + wv;
  int lane = threadIdx.x & 63;
  bool valid = wid < N;
  if (OUTP == 1 && !valid) return;

  int half = lane >> 5;
  int dq = lane & 31;  // dims dq*4 .. dq*4+3
  float a0 = 0.f, a1 = 0.f, a2 = 0.f, a3 = 0.f;
  float o0 = 0.f, o1 = 0.f, o2 = 0.f, o3 = 0.f;

  if (valid) {
    const uint2* uvb = (const uint2*)Ub;  // row stride 32 uint2
    int e0 = row_ptr[wid], e1 = row_ptr[wid + 1];
    int e = e0;
    for (; e + 8 <= e1; e += 8) {
      int s0 = col[e + half];
      int s1 = col[e + 2 + half];
      int s2 = col[e + 4 + half];
      int s3 = col[e + 6 + half];
      uint2 u0 = uvb[(size_t)s0 * 32 + dq];
      uint2 u1 = uvb[(size_t)s1 * 32 + dq];
      uint2 u2 = uvb[(size_t)s2 * 32 + dq];
      uint2 u3 = uvb[(size_t)s3 * 32 + dq];
      a0 += blo(u0.x) + blo(u1.x) + blo(u2.x) + blo(u3.x);
      a1 += bhi(u0.x) + bhi(u1.x) + bhi(u2.x) + bhi(u3.x);
      a2 += blo(u0.y) + blo(u1.y) + blo(u2.y) + blo(u3.y);
      a3 += bhi(u0.y) + bhi(u1.y) + bhi(u2.y) + bhi(u3.y);
    }
    for (; e + 2 <= e1; e += 2) {
      uint2 u = uvb[(size_t)col[e + half] * 32 + dq];
      a0 += blo(u.x);
      a1 += bhi(u.x);
      a2 += blo(u.y);
      a3 += bhi(u.y);
    }
    if (e < e1 && half == 0) {
      uint2 u = uvb[(size_t)col[e] * 32 + dq];
      a0 += blo(u.x);
      a1 += bhi(u.x);
      a2 += blo(u.y);
      a3 += bhi(u.y);
    }
    // combine halves (both halves end holding the full sums)
    a0 += __shfl_xor(a0, 32);
    a1 += __shfl_xor(a1, 32);
    a2 += __shfl_xor(a2, 32);
    a3 += __shfl_xor(a3, 32);

    float inv = 1.f / fmaxf((float)(e1 - e0), 1.f);
    float4 vv = *(const float4*)(V + (size_t)wid * D_H + dq * 4);
    float4 bb = *(const float4*)(bias + dq * 4);
    o0 = fmaxf(a0 * inv + vv.x + bb.x, 0.f);
    o1 = fmaxf(a1 * inv + vv.y + bb.y, 0.f);
    o2 = fmaxf(a2 * inv + vv.z + bb.z, 0.f);
    o3 = fmaxf(a3 * inv + vv.w + bb.w, 0.f);

    if (OUTP) {
      // pair write: half 0 writes hi words, half 1 writes lo words (8 B each)
      unsigned int w0, w1;
      if (half == 0) {
        unsigned int x0 = __float_as_uint(o0), x1 = __float_as_uint(o1);
        unsigned int x2 = __float_as_uint(o2), x3 = __float_as_uint(o3);
        w0 = (x0 >> 16) | (x1 & 0xffff0000u);
        w1 = (x2 >> 16) | (x3 & 0xffff0000u);
      } else {
        unsigned short h, lq0, lq1, lq2, lq3;
        split_bf16(o0, h, lq0);
        split_bf16(o1, h, lq1);
        split_bf16(o2, h, lq2);
        split_bf16(o3, h, lq3);
        w0 = (unsigned int)lq0 | ((unsigned int)lq1 << 16);
        w1 = (unsigned int)lq2 | ((unsigned int)lq3 << 16);
      }
      *(uint2*)((char*)Hp + (size_t)wid * 512 + half * 256 + dq * 8) = make_uint2(w0, w1);
    } else {
      if (half == 0)
        *(float4*)(V + (size_t)wid * D_H + dq * 4) = make_float4(o0, o1, o2, o3);
    }
  }

  if (OUTP == 0) {
    float sc = -3.0e38f;
    float4 w = valid ? *(const float4*)(watt + dq * 4) : make_float4(0.f, 0.f, 0.f, 0.f);
    float p = o0 * w.x + o1 * w.y + o2 * w.z + o3 * w.w;
#pragma unroll
    for (int off = 1; off < 32; off <<= 1) p += __shfl_xor(p, off);
    if (valid) {
      sc = p + batt[0];
      if (lane == 0) scores[wid] = sc;
    }
    if (lane == 0) smax[wv] = sc;
    __syncthreads();
    if (threadIdx.x == 0)
      partmax[blockIdx.x] = fmaxf(fmaxf(smax[0], smax[1]), fmaxf(smax[2], smax[3]));
  }
}

// ---------------- attention readout tail ----------------

__global__ __launch_bounds__(256) void k_redmax(const float* __restrict__ partmax, int PB,
                                                float* __restrict__ red) {
  __shared__ float sm[256];
  int t = threadIdx.x;
  float m = -3.0e38f;
  for (int i = t; i < PB; i += 256) m = fmaxf(m, partmax[i]);
  sm[t] = m;
  __syncthreads();
  for (int off = 128; off > 0; off >>= 1) {
    if (t < off) sm[t] = fmaxf(sm[t], sm[t + off]);
    __syncthreads();
  }
  if (t == 0) {
    red[0] = sm[0];
    red[1] = 0.f;
  }
  for (int i = t; i < 1024; i += 256) red[2 + i] = 0.f;
}

__global__ __launch_bounds__(256) void k_pool(const float* __restrict__ h,
                                              const float* __restrict__ scores,
                                              const int* __restrict__ batch,
                                              float* __restrict__ red, int N, int nblocks) {
  __shared__ float pl[4][1024];
  __shared__ float zp[4];
  int t = threadIdx.x;
  int w = t >> 6, lane = t & 63;
  for (int i = lane; i < 1024; i += 64) pl[w][i] = 0.f;
  float M = red[0];
  float zacc = 0.f;
  const float2* hv = (const float2*)h;
  int stride = nblocks * 4;
  for (int node = blockIdx.x * 4 + w; node < N; node += stride) {
    float wgt = __expf(scores[node] - M);
    int b = batch[node];
    float2 v = hv[(size_t)node * 64 + lane];
    pl[w][b * 128 + lane * 2] += v.x * wgt;
    pl[w][b * 128 + lane * 2 + 1] += v.y * wgt;
    zacc += wgt;
  }
  if (lane == 0) zp[w] = zacc;
  __syncthreads();
  for (int i = t; i < 1024; i += 256) {
    float s = pl[0][i] + pl[1][i] + pl[2][i] + pl[3][i];
    atomicAdd(&red[2 + i], s);
  }
  if (t == 0) atomicAdd(&red[1], zp[0] + zp[1] + zp[2] + zp[3]);
}

__global__ __launch_bounds__(512) void k_out(const float* __restrict__ red,
                                             const float* __restrict__ Wout,
                                             const float* __restrict__ bout,
                                             float* __restrict__ out) {
  int t = threadIdx.x;
  int gIdx = t >> 6, o = t & 63;
  float invZ = 1.f / red[1];
  const float* p = red + 2 + gIdx * 128;
  const float* wr = Wout + (size_t)o * 128;
  float acc = 0.f;
  for (int k = 0; k < 128; ++k) acc = fmaf(p[k], wr[k], acc);
  out[gIdx * 64 + o] = acc * invZ + bout[o];
}

// ---------------- launcher ----------------

extern "C" void kernel_launch(void* const* d_in, const int* in_sizes, int n_in,
                              void* d_out, int out_size, void* d_ws, size_t ws_size,
                              hipStream_t stream) {
  const float* x     = (const float*)d_in[0];
  const int*   ei    = (const int*)d_in[1];
  const int*   batch = (const int*)d_in[2];
  const float* W_emb = (const float*)d_in[3];
  const float* b_emb = (const float*)d_in[4];
  const float* Wl0   = (const float*)d_in[5];
  const float* bl0   = (const float*)d_in[6];
  const float* Wr0   = (const float*)d_in[7];
  const float* Wl1   = (const float*)d_in[8];
  const float* bl1   = (const float*)d_in[9];
  const float* Wr1   = (const float*)d_in[10];
  const float* W_att = (const float*)d_in[11];
  const float* b_att = (const float*)d_in[12];
  const float* W_out = (const float*)d_in[13];
  const float* b_out = (const float*)d_in[14];
  float* out = (float*)d_out;

  const int DIN = 300;
  int N = in_sizes[0] / DIN;
  int E = in_sizes[1] / 2;
  int Npad = (N + 127) & ~127;
  int NB = (N + 255) / 256;

  char* wsp = (char*)d_ws;
  size_t off = 0;
  auto carve = [&](size_t bytes) -> void* {
    void* p = wsp + off;
    off += (bytes + 255) & ~(size_t)255;
    return p;
  };
  unsigned short* P  = (unsigned short*)carve((size_t)Npad * 512);  // h pairs
  unsigned short* Ub = (unsigned short*)carve((size_t)Npad * 256);  // A@Wl bf16
  float*          V  = (float*)carve((size_t)Npad * 512);           // A@Wr fp32 / h2
  unsigned short* WembP = (unsigned short*)carve((size_t)128 * 640 * 2);
  unsigned short* WP0l  = (unsigned short*)carve((size_t)128 * 256 * 2);
  unsigned short* WP0r  = (unsigned short*)carve((size_t)128 * 256 * 2);
  unsigned short* WP1l  = (unsigned short*)carve((size_t)128 * 256 * 2);
  unsigned short* WP1r  = (unsigned short*)carve((size_t)128 * 256 * 2);
  int*   colA    = (int*)carve((size_t)E * 4);
  unsigned int* tmpE = (unsigned int*)carve((size_t)E * 4);
  int*   row_ptr = (int*)carve((size_t)(N + 1) * 4);
  int*   bucketCnt  = (int*)carve((size_t)(NB + 1) * 4);
  int*   bucketBase = (int*)carve((size_t)(NB + 1) * 4);
  int*   cursor     = (int*)carve((size_t)(NB + 1) * 4);
  float* scores  = (float*)carve((size_t)N * 4);
  int aggBlocks = (N + 3) / 4;
  float* partmax = (float*)carve((size_t)aggBlocks * 4);
  float* red     = (float*)carve((size_t)(2 + 1024) * 4);

  const int* srcv = ei;
  const int* dstv = ei + E;

  hipMemsetAsync(bucketCnt, 0, (size_t)NB * 4, stream);
  k_hist<<<512, 256, 0, stream>>>(dstv, bucketCnt, E);
  k_bucketscan<<<1, 256, 0, stream>>>(bucketCnt, NB, bucketBase, cursor, row_ptr, N, E);
  k_binscatter<<<256, 256, 0, stream>>>(srcv, dstv, cursor, tmpE, E);
  k_localcsr<<<NB, 256, 0, stream>>>(tmpE, bucketBase, row_ptr, colA, N);
  k_wsplit<<<(128 * 320 + 4 * 16384 + 255) / 256, 256, 0, stream>>>(
      W_emb, Wl0, Wr0, Wl1, Wr1, WembP, WP0l, WP0r, WP1l, WP1r);

  dim3 gemb(Npad / 128, 2);
  k_emb<<<gemb, 512, 0, stream>>>(x, WembP, b_emb, P, N);

  dim3 gconv(Npad / 128, 2);
  // conv0 + aggfin -> pair P
  k_conv<<<gconv, 512, 0, stream>>>(P, WP0l, WP0r, Ub, V);
  k_aggfin<1><<<aggBlocks, 256, 0, stream>>>(Ub, V, bl0, row_ptr, colA, P,
                                             nullptr, nullptr, nullptr, nullptr, N);
  // conv1 + aggfin (fp32 in-place into V) + fused score
  k_conv<<<gconv, 512, 0, stream>>>(P, WP1l, WP1r, Ub, V);
  k_aggfin<0><<<aggBlocks, 256, 0, stream>>>(Ub, V, bl1, row_ptr, colA, nullptr,
                                             W_att, b_att, scores, partmax, N);

  const float* h2 = (const float*)V;
  k_redmax<<<1, 256, 0, stream>>>(partmax, aggBlocks, red);
  k_pool<<<256, 256, 0, stream>>>(h2, scores, batch, red, N, 256);
  k_out<<<1, 512, 0, stream>>>(red, W_out, b_out, out);
}